// Round 1
// baseline (691.551 us; speedup 1.0000x reference)
//
#include <hip/hip_runtime.h>
#include <math.h>

#define B 16
#define N 1024
#define F_IN 80
#define D 64
#define DEPTH 4
#define BN_EPS 1e-5f

// h = relu(X @ W0)   X:(B*N,80)  W0:(80,64)
__global__ void k_h0(const float* __restrict__ X, const float* __restrict__ W0,
                     float* __restrict__ h) {
    int row = blockIdx.x;        // b*N+n
    int d   = threadIdx.x;       // 0..63
    __shared__ float xr[F_IN];
    const float* xp = X + (size_t)row * F_IN;
    if (d < F_IN) xr[d] = xp[d];
    if (d + 64 < F_IN) xr[d + 64] = xp[d + 64];
    __syncthreads();
    float acc = 0.f;
#pragma unroll
    for (int f = 0; f < F_IN; ++f) acc += xr[f] * W0[f * D + d];
    h[(size_t)row * D + d] = fmaxf(acc, 0.f);
}

// hW = relu(h @ Wl[i]); t1 = hW . a1; t2 = hW . a2   (one row per 64-thread block)
__global__ void k_hw(const float* __restrict__ h, const float* __restrict__ Wl,
                     const float* __restrict__ a1, const float* __restrict__ a2,
                     float* __restrict__ hW, float* __restrict__ t1,
                     float* __restrict__ t2) {
    int row = blockIdx.x;
    int d   = threadIdx.x;       // 0..63
    __shared__ float hr[D];
    hr[d] = h[(size_t)row * D + d];
    __syncthreads();
    float acc = 0.f;
#pragma unroll
    for (int k = 0; k < D; ++k) acc += hr[k] * Wl[k * D + d];
    float v = fmaxf(acc, 0.f);
    hW[(size_t)row * D + d] = v;
    float p1 = v * a1[d];
    float p2 = v * a2[d];
#pragma unroll
    for (int off = 32; off > 0; off >>= 1) {
        p1 += __shfl_down(p1, off);
        p2 += __shfl_down(p2, off);
    }
    if (d == 0) { t1[row] = p1; t2[row] = p2; }
}

// Per (b,n): e[m] = adj>0 ? relu(t1[n]+t2[m]) : 0 ; att = softmax(e) over m
// emb[d] = sum_m att[m]*hW[b,m,d] ; h[b,n,:] = root>0 ? emb : h
__global__ void k_att(const float* __restrict__ hW, const float* __restrict__ t1,
                      const float* __restrict__ t2, const int* __restrict__ adj,
                      const float* __restrict__ root_list, int ridx,
                      float* __restrict__ h) {
    int b = blockIdx.x >> 10;
    int n = blockIdx.x & (N - 1);
    int t = threadIdx.x;         // 0..255
    __shared__ float w[N];
    __shared__ float red[8];
    __shared__ float part[4][D];

    float t1v = t1[b * N + n];
    const int*   arow = adj + ((size_t)(b * N + n)) * N;
    const float* t2b  = t2 + b * N;

    float lmax = 0.f;            // all e >= 0 after masking
#pragma unroll
    for (int j = 0; j < 4; ++j) {
        int m = t + j * 256;
        float e = (arow[m] > 0) ? fmaxf(t1v + t2b[m], 0.f) : 0.f;
        w[m] = e;
        lmax = fmaxf(lmax, e);
    }
#pragma unroll
    for (int off = 32; off > 0; off >>= 1) lmax = fmaxf(lmax, __shfl_down(lmax, off));
    int wid = t >> 6, lane = t & 63;
    if (lane == 0) red[wid] = lmax;
    __syncthreads();
    float bmax = fmaxf(fmaxf(red[0], red[1]), fmaxf(red[2], red[3]));

    float lsum = 0.f;
#pragma unroll
    for (int j = 0; j < 4; ++j) {
        int m = t + j * 256;
        float e = __expf(w[m] - bmax);
        w[m] = e;
        lsum += e;
    }
#pragma unroll
    for (int off = 32; off > 0; off >>= 1) lsum += __shfl_down(lsum, off);
    if (lane == 0) red[4 + wid] = lsum;
    __syncthreads();
    float inv = 1.0f / (red[4] + red[5] + red[6] + red[7]);

    // matvec: 4 groups of 64 threads, group g covers m in [g*256, g*256+256)
    int d = t & 63, g = t >> 6;
    const float* hwb = hW + (size_t)b * N * D;
    float acc = 0.f;
    int m0 = g * 256;
#pragma unroll 4
    for (int m = m0; m < m0 + 256; ++m) acc += w[m] * hwb[(size_t)m * D + d];
    part[g][d] = acc;
    __syncthreads();
    if (t < D) {
        float emb = (part[0][t] + part[1][t] + part[2][t] + part[3][t]) * inv;
        float rv  = root_list[((size_t)b * DEPTH + ridx) * N + n];
        size_t idx = ((size_t)(b * N + n)) * D + t;
        float h0v = h[idx];
        h[idx] = (rv > 0.f) ? emb : h0v;
    }
}

// Final pooling + BN-MLP + 2-class softmax, one block per batch.
__global__ void k_pool(const float* __restrict__ h, const float* __restrict__ root_list,
                       const float* __restrict__ P,
                       const float* __restrict__ pW1, const float* __restrict__ pb1,
                       const float* __restrict__ g1, const float* __restrict__ be1,
                       const float* __restrict__ m1, const float* __restrict__ v1,
                       const float* __restrict__ pW2, const float* __restrict__ pb2,
                       const float* __restrict__ g2, const float* __restrict__ be2,
                       const float* __restrict__ m2, const float* __restrict__ v2,
                       const float* __restrict__ pW3, const float* __restrict__ pb3,
                       float* __restrict__ out) {
    int b = blockIdx.x;
    int t = threadIdx.x;         // 0..255
    __shared__ float pv[D];
    __shared__ float w[N];
    __shared__ float red[8];
    __shared__ float part[4][D];
    __shared__ float od[D];
    __shared__ float x1[128];
    __shared__ float x2[64];
    __shared__ float lg[2];

    if (t < D) pv[t] = P[t];
    __syncthreads();

    const float* hb = h + (size_t)b * N * D;
    const float* rl = root_list + ((size_t)b * DEPTH + 1) * N;

    float lmax = -3.4e38f;
    for (int j = 0; j < 4; ++j) {
        int n = t + j * 256;
        float dot = 0.f;
#pragma unroll
        for (int d2 = 0; d2 < D; ++d2) dot += hb[(size_t)n * D + d2] * pv[d2];
        float e = fmaxf(dot, 0.f);
        if (!(rl[n] > 0.f)) e = -9e15f;
        w[n] = e;
        lmax = fmaxf(lmax, e);
    }
#pragma unroll
    for (int off = 32; off > 0; off >>= 1) lmax = fmaxf(lmax, __shfl_down(lmax, off));
    int wid = t >> 6, lane = t & 63;
    if (lane == 0) red[wid] = lmax;
    __syncthreads();
    float bmax = fmaxf(fmaxf(red[0], red[1]), fmaxf(red[2], red[3]));

    float lsum = 0.f;
    for (int j = 0; j < 4; ++j) {
        int n = t + j * 256;
        float e = __expf(w[n] - bmax);
        w[n] = e;
        lsum += e;
    }
#pragma unroll
    for (int off = 32; off > 0; off >>= 1) lsum += __shfl_down(lsum, off);
    if (lane == 0) red[4 + wid] = lsum;
    __syncthreads();
    float inv = 1.0f / (red[4] + red[5] + red[6] + red[7]);

    int d = t & 63, g = t >> 6;
    float acc = 0.f;
    int n0 = g * 256;
    for (int n = n0; n < n0 + 256; ++n) acc += w[n] * hb[(size_t)n * D + d];
    part[g][d] = acc;
    __syncthreads();
    if (t < D) od[t] = (part[0][t] + part[1][t] + part[2][t] + part[3][t]) * inv;
    __syncthreads();

    if (t < 128) {
        float s = pb1[t];
#pragma unroll
        for (int k = 0; k < D; ++k) s += od[k] * pW1[k * 128 + t];
        s = (s - m1[t]) * rsqrtf(v1[t] + BN_EPS) * g1[t] + be1[t];
        x1[t] = fmaxf(s, 0.f);
    }
    __syncthreads();
    if (t < 64) {
        float s = pb2[t];
#pragma unroll
        for (int k = 0; k < 128; ++k) s += x1[k] * pW2[k * 64 + t];
        s = (s - m2[t]) * rsqrtf(v2[t] + BN_EPS) * g2[t] + be2[t];
        x2[t] = fmaxf(s, 0.f);
    }
    __syncthreads();
    if (t < 2) {
        float s = pb3[t];
#pragma unroll
        for (int k = 0; k < 64; ++k) s += x2[k] * pW3[k * 2 + t];
        lg[t] = fmaxf(s, 0.f);
    }
    __syncthreads();
    if (t < 2) {
        float mm = fmaxf(lg[0], lg[1]);
        float e0 = __expf(lg[0] - mm), e1 = __expf(lg[1] - mm);
        out[b * 2 + t] = ((t == 0) ? e0 : e1) / (e0 + e1);
    }
}

extern "C" void kernel_launch(void* const* d_in, const int* in_sizes, int n_in,
                              void* d_out, int out_size, void* d_ws, size_t ws_size,
                              hipStream_t stream) {
    const int*   adj = (const int*)d_in[0];
    const float* X   = (const float*)d_in[1];
    const float* rl  = (const float*)d_in[2];
    const float* W0  = (const float*)d_in[3];
    const float* Wl  = (const float*)d_in[4];
    const float* a1l = (const float*)d_in[5];
    const float* a2l = (const float*)d_in[6];
    const float* P   = (const float*)d_in[7];
    const float* pW1 = (const float*)d_in[8];
    const float* pb1 = (const float*)d_in[9];
    const float* g1  = (const float*)d_in[10];
    const float* be1 = (const float*)d_in[11];
    const float* m1  = (const float*)d_in[12];
    const float* v1  = (const float*)d_in[13];
    const float* pW2 = (const float*)d_in[14];
    const float* pb2 = (const float*)d_in[15];
    const float* g2  = (const float*)d_in[16];
    const float* be2 = (const float*)d_in[17];
    const float* m2  = (const float*)d_in[18];
    const float* v2  = (const float*)d_in[19];
    const float* pW3 = (const float*)d_in[20];
    const float* pb3 = (const float*)d_in[21];
    float* out = (float*)d_out;

    float* h  = (float*)d_ws;                 // B*N*D
    float* hW = h  + (size_t)B * N * D;       // B*N*D
    float* t1 = hW + (size_t)B * N * D;       // B*N
    float* t2 = t1 + (size_t)B * N;           // B*N

    k_h0<<<B * N, 64, 0, stream>>>(X, W0, h);
    for (int i = 0; i < DEPTH - 1; ++i) {
        k_hw<<<B * N, 64, 0, stream>>>(h, Wl + i * D * D, a1l + i * D, a2l + i * D,
                                       hW, t1, t2);
        k_att<<<B * N, 256, 0, stream>>>(hW, t1, t2, adj, rl, DEPTH - 1 - i, h);
    }
    k_pool<<<B, 256, 0, stream>>>(h, rl, P, pW1, pb1, g1, be1, m1, v1,
                                  pW2, pb2, g2, be2, m2, v2, pW3, pb3, out);
}

// Round 3
// 374.296 us; speedup vs baseline: 1.8476x; 1.8476x over previous
//
#include <hip/hip_runtime.h>
#include <hip/hip_bf16.h>
#include <math.h>

#define B 16
#define N 1024
#define F_IN 80
#define D 64
#define DEPTH 4
#define BN_EPS 1e-5f
#define WPAD 1028   // u32 row stride for w LDS tile (16B-aligned rows, spread banks)

typedef __attribute__((ext_vector_type(8))) short  short8v;
typedef __attribute__((ext_vector_type(4))) float  float4v;
typedef __attribute__((ext_vector_type(4))) unsigned int uint4v;

union FragU { uint4v u; short8v s; };

__device__ __forceinline__ unsigned short f2bf_rne(float x) {
    unsigned int u = __float_as_uint(x);
    unsigned int r = u + 0x7FFFu + ((u >> 16) & 1u);
    return (unsigned short)(r >> 16);
}
__device__ __forceinline__ float bf2f(unsigned short b) {
    return __uint_as_float(((unsigned int)b) << 16);
}
// pack value as (bf16 hi << 16) | bf16(residual)
__device__ __forceinline__ unsigned int pack_split(float w) {
    unsigned short hb = f2bf_rne(w);
    unsigned short lb = f2bf_rne(w - bf2f(hb));
    return (((unsigned int)hb) << 16) | (unsigned int)lb;
}

// ---------------- adj bit-pack: 64 int32 -> 1 u64 ----------------
__global__ void k_pack(const int* __restrict__ adj, unsigned long long* __restrict__ packA) {
    int gw   = (blockIdx.x * blockDim.x + threadIdx.x) >> 6;  // global wave id 0..4095
    int lane = threadIdx.x & 63;
    for (int it = 0; it < 64; ++it) {
        size_t word = (size_t)gw * 64 + it;
        unsigned long long m = __ballot(adj[word * 64 + lane] > 0);
        if (lane == 0) packA[word] = m;
    }
}

// ---------------- h = relu(X @ W0) ----------------
__global__ void k_h0(const float* __restrict__ X, const float* __restrict__ W0,
                     float* __restrict__ h) {
    int row = blockIdx.x;
    int d   = threadIdx.x;
    __shared__ float xr[F_IN];
    const float* xp = X + (size_t)row * F_IN;
    if (d < F_IN) xr[d] = xp[d];
    if (d + 64 < F_IN) xr[d + 64] = xp[d + 64];
    __syncthreads();
    float acc = 0.f;
#pragma unroll
    for (int f = 0; f < F_IN; ++f) acc += xr[f] * W0[f * D + d];
    h[(size_t)row * D + d] = fmaxf(acc, 0.f);
}

// ---------------- hW = relu(h@Wl) -> packed B-fragment layout; t1,t2 ----------------
// hWf flat index per batch: ((dt*32 + ks)*64 + lane)*8 + i
//   holds hW[32*ks + 8*(lane>>4) + i][16*dt + (lane&15)] as (bf16hi<<16)|bf16lo
__global__ void k_hw(const float* __restrict__ h, const float* __restrict__ Wl,
                     const float* __restrict__ a1, const float* __restrict__ a2,
                     unsigned int* __restrict__ hWf, float* __restrict__ t1,
                     float* __restrict__ t2) {
    int row = blockIdx.x;             // b*N + n
    int b = row >> 10, n = row & (N - 1);
    int d = threadIdx.x;              // 0..63
    __shared__ float hr[D];
    hr[d] = h[(size_t)row * D + d];
    __syncthreads();
    float acc = 0.f;
#pragma unroll
    for (int k = 0; k < D; ++k) acc += hr[k] * Wl[k * D + d];
    float v = fmaxf(acc, 0.f);

    int ks = n >> 5, q = (n >> 3) & 3, i = n & 7, dt = d >> 4, c = d & 15;
    int flat = ((dt * 32 + ks) * 64 + (q * 16 + c)) * 8 + i;
    hWf[(size_t)b * (N * D) + flat] = pack_split(v);

    float p1 = v * a1[d];
    float p2 = v * a2[d];
#pragma unroll
    for (int off = 32; off > 0; off >>= 1) {
        p1 += __shfl_down(p1, off);
        p2 += __shfl_down(p2, off);
    }
    if (d == 0) { t1[row] = p1; t2[row] = p2; }
}

// ---------------- attention tile: 16 rows per block, MFMA split-bf16 ----------------
__global__ __launch_bounds__(256, 2) void k_att(
    const unsigned int* __restrict__ hWf, const float* __restrict__ t1,
    const float* __restrict__ t2, const int* __restrict__ adj,
    const unsigned long long* __restrict__ packA,
    const float* __restrict__ root_list, int ridx, float* __restrict__ h)
{
    int b  = blockIdx.x >> 6;
    int n0 = (blockIdx.x & 63) << 4;
    int t = threadIdx.x;
    int lane = t & 63, wid = t >> 6;

    __shared__ unsigned int w_u32[16][WPAD];
    __shared__ float t2s[N];
    __shared__ float red[16][4];
    __shared__ float invs[16];

#pragma unroll
    for (int j = 0; j < 4; ++j) t2s[t + 256 * j] = t2[b * N + t + 256 * j];
    __syncthreads();

    // ---- phase 1: e = mask ? relu(t1+t2) : 0 ; w = exp(e) (no max-sub; e bounded) ----
    for (int r = 0; r < 16; ++r) {
        int n = n0 + r;
        float t1v = t1[b * N + n];
        float lsum = 0.f;
        if (packA) {
            const unsigned long long* prow = packA + ((size_t)(b * N + n)) * 16;
#pragma unroll
            for (int j = 0; j < 4; ++j) {
                int m = t + 256 * j;
                unsigned long long word = prow[m >> 6];
                int bit = (int)((word >> (m & 63)) & 1ULL);
                float e = bit ? fmaxf(t1v + t2s[m], 0.f) : 0.f;
                float wv = __expf(e);
                lsum += wv;
                w_u32[r][m] = pack_split(wv);
            }
        } else {
            const int* arow = adj + ((size_t)(b * N + n)) * N;
#pragma unroll
            for (int j = 0; j < 4; ++j) {
                int m = t + 256 * j;
                float e = (arow[m] > 0) ? fmaxf(t1v + t2s[m], 0.f) : 0.f;
                float wv = __expf(e);
                lsum += wv;
                w_u32[r][m] = pack_split(wv);
            }
        }
#pragma unroll
        for (int off = 32; off > 0; off >>= 1) lsum += __shfl_down(lsum, off);
        if (lane == 0) red[r][wid] = lsum;
    }
    __syncthreads();
    if (t < 16) invs[t] = 1.0f / (red[t][0] + red[t][1] + red[t][2] + red[t][3]);
    __syncthreads();

    // ---- phase 2: emb(16x64) = att(16x1024) @ hW(1024x64), wave wid owns d-tile wid ----
    int r16 = lane & 15, q = lane >> 4;
    const unsigned int* Bbase = hWf + (size_t)b * (N * D) + (size_t)(wid * 32) * 64 * 8;
    float4v acc = {0.f, 0.f, 0.f, 0.f};
#pragma unroll 2
    for (int ks = 0; ks < 32; ++ks) {
        const unsigned int* ap = &w_u32[r16][ks * 32 + q * 8];
        uint4v a0 = *(const uint4v*)ap;
        uint4v a1v = *(const uint4v*)(ap + 4);
        const unsigned int* bp = Bbase + (size_t)(ks * 64 + lane) * 8;
        uint4v b0 = *(const uint4v*)bp;
        uint4v b1 = *(const uint4v*)(bp + 4);

        FragU ahi, alo, bhi, blo;
        ahi.u = (uint4v){(a0.y & 0xFFFF0000u) | (a0.x >> 16),
                         (a0.w & 0xFFFF0000u) | (a0.z >> 16),
                         (a1v.y & 0xFFFF0000u) | (a1v.x >> 16),
                         (a1v.w & 0xFFFF0000u) | (a1v.z >> 16)};
        alo.u = (uint4v){(a0.y << 16) | (a0.x & 0xFFFFu),
                         (a0.w << 16) | (a0.z & 0xFFFFu),
                         (a1v.y << 16) | (a1v.x & 0xFFFFu),
                         (a1v.w << 16) | (a1v.z & 0xFFFFu)};
        bhi.u = (uint4v){(b0.y & 0xFFFF0000u) | (b0.x >> 16),
                         (b0.w & 0xFFFF0000u) | (b0.z >> 16),
                         (b1.y & 0xFFFF0000u) | (b1.x >> 16),
                         (b1.w & 0xFFFF0000u) | (b1.z >> 16)};
        blo.u = (uint4v){(b0.y << 16) | (b0.x & 0xFFFFu),
                         (b0.w << 16) | (b0.z & 0xFFFFu),
                         (b1.y << 16) | (b1.x & 0xFFFFu),
                         (b1.w << 16) | (b1.z & 0xFFFFu)};

        acc = __builtin_amdgcn_mfma_f32_16x16x32_bf16(ahi.s, bhi.s, acc, 0, 0, 0);
        acc = __builtin_amdgcn_mfma_f32_16x16x32_bf16(ahi.s, blo.s, acc, 0, 0, 0);
        acc = __builtin_amdgcn_mfma_f32_16x16x32_bf16(alo.s, bhi.s, acc, 0, 0, 0);
    }

    // ---- epilogue: C[row=(lane>>4)*4+reg][col=lane&15]; root-gated in-place update ----
    int col = lane & 15;
    int rbase = (lane >> 4) * 4;
    int dcol = wid * 16 + col;
    const float* rl = root_list + ((size_t)b * DEPTH + ridx) * N;
#pragma unroll
    for (int reg = 0; reg < 4; ++reg) {
        int r = rbase + reg;
        int n = n0 + r;
        if (rl[n] > 0.f) h[((size_t)(b * N + n)) * D + dcol] = acc[reg] * invs[r];
    }
}

// ---------------- pooling + BN-MLP + softmax ----------------
__global__ void k_pool(const float* __restrict__ h, const float* __restrict__ root_list,
                       const float* __restrict__ P,
                       const float* __restrict__ pW1, const float* __restrict__ pb1,
                       const float* __restrict__ g1, const float* __restrict__ be1,
                       const float* __restrict__ m1, const float* __restrict__ v1,
                       const float* __restrict__ pW2, const float* __restrict__ pb2,
                       const float* __restrict__ g2, const float* __restrict__ be2,
                       const float* __restrict__ m2, const float* __restrict__ v2,
                       const float* __restrict__ pW3, const float* __restrict__ pb3,
                       float* __restrict__ out) {
    int b = blockIdx.x;
    int t = threadIdx.x;
    __shared__ float pv[D];
    __shared__ float w[N];
    __shared__ float red[8];
    __shared__ float part[4][D];
    __shared__ float od[D];
    __shared__ float x1[128];
    __shared__ float x2[64];
    __shared__ float lg[2];

    if (t < D) pv[t] = P[t];
    __syncthreads();

    const float* hb = h + (size_t)b * N * D;
    const float* rl = root_list + ((size_t)b * DEPTH + 1) * N;

    float lmax = -3.4e38f;
    for (int j = 0; j < 4; ++j) {
        int n = t + j * 256;
        float dot = 0.f;
#pragma unroll
        for (int d2 = 0; d2 < D; ++d2) dot += hb[(size_t)n * D + d2] * pv[d2];
        float e = fmaxf(dot, 0.f);
        if (!(rl[n] > 0.f)) e = -9e15f;
        w[n] = e;
        lmax = fmaxf(lmax, e);
    }
#pragma unroll
    for (int off = 32; off > 0; off >>= 1) lmax = fmaxf(lmax, __shfl_down(lmax, off));
    int wid = t >> 6, lane = t & 63;
    if (lane == 0) red[wid] = lmax;
    __syncthreads();
    float bmax = fmaxf(fmaxf(red[0], red[1]), fmaxf(red[2], red[3]));

    float lsum = 0.f;
    for (int j = 0; j < 4; ++j) {
        int n = t + j * 256;
        float e = __expf(w[n] - bmax);
        w[n] = e;
        lsum += e;
    }
#pragma unroll
    for (int off = 32; off > 0; off >>= 1) lsum += __shfl_down(lsum, off);
    if (lane == 0) red[4 + wid] = lsum;
    __syncthreads();
    float inv = 1.0f / (red[4] + red[5] + red[6] + red[7]);

    int d = t & 63, g = t >> 6;
    float acc = 0.f;
    int n0 = g * 256;
    for (int n = n0; n < n0 + 256; ++n) acc += w[n] * hb[(size_t)n * D + d];
    part[g][d] = acc;
    __syncthreads();
    if (t < D) od[t] = (part[0][t] + part[1][t] + part[2][t] + part[3][t]) * inv;
    __syncthreads();

    if (t < 128) {
        float s = pb1[t];
#pragma unroll
        for (int k = 0; k < D; ++k) s += od[k] * pW1[k * 128 + t];
        s = (s - m1[t]) * rsqrtf(v1[t] + BN_EPS) * g1[t] + be1[t];
        x1[t] = fmaxf(s, 0.f);
    }
    __syncthreads();
    if (t < 64) {
        float s = pb2[t];
#pragma unroll
        for (int k = 0; k < 128; ++k) s += x1[k] * pW2[k * 64 + t];
        s = (s - m2[t]) * rsqrtf(v2[t] + BN_EPS) * g2[t] + be2[t];
        x2[t] = fmaxf(s, 0.f);
    }
    __syncthreads();
    if (t < 2) {
        float s = pb3[t];
#pragma unroll
        for (int k = 0; k < 64; ++k) s += x2[k] * pW3[k * 2 + t];
        lg[t] = fmaxf(s, 0.f);
    }
    __syncthreads();
    if (t < 2) {
        float mm = fmaxf(lg[0], lg[1]);
        float e0 = __expf(lg[0] - mm), e1 = __expf(lg[1] - mm);
        out[b * 2 + t] = ((t == 0) ? e0 : e1) / (e0 + e1);
    }
}

extern "C" void kernel_launch(void* const* d_in, const int* in_sizes, int n_in,
                              void* d_out, int out_size, void* d_ws, size_t ws_size,
                              hipStream_t stream) {
    const int*   adj = (const int*)d_in[0];
    const float* X   = (const float*)d_in[1];
    const float* rl  = (const float*)d_in[2];
    const float* W0  = (const float*)d_in[3];
    const float* Wl  = (const float*)d_in[4];
    const float* a1l = (const float*)d_in[5];
    const float* a2l = (const float*)d_in[6];
    const float* P   = (const float*)d_in[7];
    const float* pW1 = (const float*)d_in[8];
    const float* pb1 = (const float*)d_in[9];
    const float* g1  = (const float*)d_in[10];
    const float* be1 = (const float*)d_in[11];
    const float* m1  = (const float*)d_in[12];
    const float* v1  = (const float*)d_in[13];
    const float* pW2 = (const float*)d_in[14];
    const float* pb2 = (const float*)d_in[15];
    const float* g2  = (const float*)d_in[16];
    const float* be2 = (const float*)d_in[17];
    const float* m2  = (const float*)d_in[18];
    const float* v2  = (const float*)d_in[19];
    const float* pW3 = (const float*)d_in[20];
    const float* pb3 = (const float*)d_in[21];
    float* out = (float*)d_out;

    float*        h    = (float*)d_ws;                         // 4 MB
    unsigned int* hWf  = (unsigned int*)(h + (size_t)B * N * D);   // 4 MB
    float*        t1   = (float*)(hWf + (size_t)B * N * D);    // 64 KB
    float*        t2   = t1 + B * N;                           // 64 KB
    // packed adj needs +2 MB beyond the proven-safe 8.52 MB footprint: runtime-gated
    size_t base_bytes = (size_t)(B * N * D) * 8 + (size_t)(B * N) * 8;
    unsigned long long* packA = nullptr;
    if (ws_size >= base_bytes + (size_t)B * N * (N / 64) * 8) {
        packA = (unsigned long long*)(t2 + B * N);
        k_pack<<<1024, 256, 0, stream>>>(adj, packA);
    }

    k_h0<<<B * N, 64, 0, stream>>>(X, W0, h);
    for (int i = 0; i < DEPTH - 1; ++i) {
        k_hw<<<B * N, 64, 0, stream>>>(h, Wl + i * D * D, a1l + i * D, a2l + i * D,
                                       hWf, t1, t2);
        k_att<<<B * (N / 16), 256, 0, stream>>>(hWf, t1, t2, adj, packA, rl,
                                                DEPTH - 1 - i, h);
    }
    k_pool<<<B, 256, 0, stream>>>(h, rl, P, pW1, pb1, g1, be1, m1, v1,
                                  pW2, pb2, g2, be2, m2, v2, pW3, pb3, out);
}

// Round 7
// 330.464 us; speedup vs baseline: 2.0927x; 1.1326x over previous
//
#include <hip/hip_runtime.h>
#include <hip/hip_bf16.h>
#include <math.h>

#define B 16
#define N 1024
#define F_IN 80
#define D 64
#define DEPTH 4
#define BN_EPS 1e-5f

typedef __attribute__((ext_vector_type(8))) short  short8v;
typedef __attribute__((ext_vector_type(4))) float  float4v;

union AFrag { unsigned int u[4]; short8v s; };

__device__ __forceinline__ unsigned short f2bf_rne(float x) {
    unsigned int u = __float_as_uint(x);
    unsigned int r = u + 0x7FFFu + ((u >> 16) & 1u);
    return (unsigned short)(r >> 16);
}
__device__ __forceinline__ float bf2f(unsigned short b) {
    return __uint_as_float(((unsigned int)b) << 16);
}

// ---------------- adj bit-pack: 64 int32 -> 1 u64 ----------------
__global__ void k_pack(const int* __restrict__ adj, unsigned long long* __restrict__ packA) {
    int gw   = (blockIdx.x * blockDim.x + threadIdx.x) >> 6;
    int lane = threadIdx.x & 63;
    for (int it = 0; it < 64; ++it) {
        size_t word = (size_t)gw * 64 + it;
        unsigned long long m = __ballot(adj[word * 64 + lane] > 0);
        if (lane == 0) packA[word] = m;
    }
}

// ---------------- h = relu(X @ W0), 16 rows/block ----------------
__global__ __launch_bounds__(256) void k_h0(const float* __restrict__ X,
                                            const float* __restrict__ W0,
                                            float* __restrict__ h) {
    int b = blockIdx.x >> 6, n0 = (blockIdx.x & 63) << 4;
    int t = threadIdx.x;
    __shared__ float w0s[F_IN * D];   // 20KB
    __shared__ float xs[16 * F_IN];   // 5KB
    for (int j = t; j < F_IN * D; j += 256) w0s[j] = W0[j];
    const float* xp = X + ((size_t)(b * N + n0)) * F_IN;
    for (int j = t; j < 16 * F_IN; j += 256) xs[j] = xp[j];
    __syncthreads();
    int d = t & 63, wid = t >> 6;
    float acc[4] = {0.f, 0.f, 0.f, 0.f};
    for (int f = 0; f < F_IN; ++f) {
        float wv = w0s[f * D + d];
#pragma unroll
        for (int j = 0; j < 4; ++j) acc[j] += xs[(wid * 4 + j) * F_IN + f] * wv;
    }
    float* hp = h + ((size_t)(b * N + n0 + wid * 4)) * D + d;
#pragma unroll
    for (int j = 0; j < 4; ++j) hp[(size_t)j * D] = fmaxf(acc[j], 0.f);
}

// ---------------- hW = relu(h@Wl) -> bf16 hi/lo planes in B-frag order; t1,t2 ----------------
// plane offset for value hW[m][c]: ((kb*4+dt)*64 + lb)*8 + i
//   kb=m>>5, i=m&7, lb=((m>>3)&3)*16 + (c&15), dt=c>>4
__global__ __launch_bounds__(256) void k_hw(const float* __restrict__ h,
                                            const float* __restrict__ Wl,
                                            const float* __restrict__ a1,
                                            const float* __restrict__ a2,
                                            unsigned short* __restrict__ hWhi,
                                            unsigned short* __restrict__ hWlo,
                                            float* __restrict__ t1,
                                            float* __restrict__ t2) {
    int b = blockIdx.x >> 6, n0 = (blockIdx.x & 63) << 4;
    int t = threadIdx.x;
    __shared__ float wls[D * D];   // 16KB
    __shared__ float hs[16 * D];   // 4KB
    for (int j = t; j < D * D; j += 256) wls[j] = Wl[j];
    const float* hp = h + ((size_t)(b * N + n0)) * D;
    for (int j = t; j < 16 * D; j += 256) hs[j] = hp[j];
    __syncthreads();
    int d = t & 63, wid = t >> 6;
    float acc[4] = {0.f, 0.f, 0.f, 0.f};
    for (int k = 0; k < D; ++k) {
        float wv = wls[k * D + d];
#pragma unroll
        for (int j = 0; j < 4; ++j) acc[j] += hs[(wid * 4 + j) * D + k] * wv;
    }
    float a1d = a1[d], a2d = a2[d];
    unsigned short* Hb = hWhi + (size_t)b * (N * D);
    unsigned short* Lb = hWlo + (size_t)b * (N * D);
#pragma unroll
    for (int j = 0; j < 4; ++j) {
        int m = n0 + wid * 4 + j;
        float v = fmaxf(acc[j], 0.f);
        unsigned short vh = f2bf_rne(v);
        unsigned short vl = f2bf_rne(v - bf2f(vh));
        int kb = m >> 5, i = m & 7;
        int lb = ((m >> 3) & 3) * 16 + (d & 15), dt = d >> 4;
        int off = ((kb * 4 + dt) * 64 + lb) * 8 + i;
        Hb[off] = vh; Lb[off] = vl;
        float p1 = v * a1d, p2 = v * a2d;
#pragma unroll
        for (int o = 32; o > 0; o >>= 1) {
            p1 += __shfl_down(p1, o);
            p2 += __shfl_down(p2, o);
        }
        if (d == 0) { t1[b * N + m] = p1; t2[b * N + m] = p2; }
    }
}

// ---------------- fused attention: 16 rows/block, w born in A-frag regs ----------------
__global__ __launch_bounds__(256, 4) void k_att(
    const unsigned short* __restrict__ hWhi, const unsigned short* __restrict__ hWlo,
    const float* __restrict__ t1, const float* __restrict__ t2,
    const unsigned long long* __restrict__ packA,
    const float* __restrict__ root_list, int ridx, float* __restrict__ h)
{
    int vb = (blockIdx.x & 7) * 128 + (blockIdx.x >> 3);   // XCD swizzle (1024 blocks)
    int b  = vb >> 6;
    int n0 = (vb & 63) << 4;
    int t = threadIdx.x, lane = t & 63, wid = t >> 6;

    __shared__ float t2s[N];               // 4KB
    __shared__ float redsum[4][16];
    __shared__ float invs[16];
    __shared__ float4v part[4][4][64];     // 16KB: [wid][dt][lane]

    ((float4v*)t2s)[t] = ((const float4v*)(t2 + b * N))[t];
    __syncthreads();

    int r  = lane & 15;
    int qg = wid * 4 + (lane >> 4);        // 0..15: global k-subgroup within a pass
    int n  = n0 + r;
    float t1v = t1[b * N + n];
    const unsigned long long* prow = packA + ((size_t)(b * N + n)) * 16;
    const short8v* BH = (const short8v*)(hWhi + (size_t)b * (N * D));
    const short8v* BL = (const short8v*)(hWlo + (size_t)b * (N * D));

    float4v acc0 = {0,0,0,0}, acc1 = {0,0,0,0}, acc2 = {0,0,0,0}, acc3 = {0,0,0,0};
    float lsum = 0.f;

#pragma unroll
    for (int p = 0; p < 8; ++p) {
        int kb = p * 4 + wid;              // this wave's 32-wide k-block
        int bi = (kb * 4) * 64 + lane;
        short8v bh0 = BH[bi], bh1 = BH[bi + 64], bh2 = BH[bi + 128], bh3 = BH[bi + 192];
        short8v bl0 = BL[bi], bl1 = BL[bi + 64], bl2 = BL[bi + 128], bl3 = BL[bi + 192];

        unsigned long long word = prow[p * 2 + (qg >> 3)];
        unsigned int mbyte = (unsigned int)(word >> ((qg & 7) * 8)) & 0xFFu;

        const float* t2p = t2s + p * 128 + qg * 8;
        float4v ta = ((const float4v*)t2p)[0];
        float4v tb = ((const float4v*)t2p)[1];

        float wv[8];
#pragma unroll
        for (int i = 0; i < 8; ++i) {
            float t2v = (i < 4) ? ta[i & 3] : tb[i & 3];
            float e = ((mbyte >> i) & 1u) ? fmaxf(t1v + t2v, 0.f) : 0.f;
            float w = __expf(e);
            wv[i] = w;
            lsum += w;
        }

        AFrag fh, fl;
#pragma unroll
        for (int i = 0; i < 4; ++i) {
            unsigned short h0 = f2bf_rne(wv[2 * i]);
            unsigned short h1 = f2bf_rne(wv[2 * i + 1]);
            unsigned short l0 = f2bf_rne(wv[2 * i] - bf2f(h0));
            unsigned short l1 = f2bf_rne(wv[2 * i + 1] - bf2f(h1));
            fh.u[i] = (unsigned int)h0 | ((unsigned int)h1 << 16);
            fl.u[i] = (unsigned int)l0 | ((unsigned int)l1 << 16);
        }

        acc0 = __builtin_amdgcn_mfma_f32_16x16x32_bf16(fh.s, bh0, acc0, 0, 0, 0);
        acc0 = __builtin_amdgcn_mfma_f32_16x16x32_bf16(fh.s, bl0, acc0, 0, 0, 0);
        acc0 = __builtin_amdgcn_mfma_f32_16x16x32_bf16(fl.s, bh0, acc0, 0, 0, 0);
        acc1 = __builtin_amdgcn_mfma_f32_16x16x32_bf16(fh.s, bh1, acc1, 0, 0, 0);
        acc1 = __builtin_amdgcn_mfma_f32_16x16x32_bf16(fh.s, bl1, acc1, 0, 0, 0);
        acc1 = __builtin_amdgcn_mfma_f32_16x16x32_bf16(fl.s, bh1, acc1, 0, 0, 0);
        acc2 = __builtin_amdgcn_mfma_f32_16x16x32_bf16(fh.s, bh2, acc2, 0, 0, 0);
        acc2 = __builtin_amdgcn_mfma_f32_16x16x32_bf16(fh.s, bl2, acc2, 0, 0, 0);
        acc2 = __builtin_amdgcn_mfma_f32_16x16x32_bf16(fl.s, bh2, acc2, 0, 0, 0);
        acc3 = __builtin_amdgcn_mfma_f32_16x16x32_bf16(fh.s, bh3, acc3, 0, 0, 0);
        acc3 = __builtin_amdgcn_mfma_f32_16x16x32_bf16(fh.s, bl3, acc3, 0, 0, 0);
        acc3 = __builtin_amdgcn_mfma_f32_16x16x32_bf16(fl.s, bh3, acc3, 0, 0, 0);
    }

    // per-row softmax denominators: lanes {l, l^16, l^32, l^48} share a row
    lsum += __shfl_xor(lsum, 16);
    lsum += __shfl_xor(lsum, 32);
    if (lane < 16) redsum[wid][lane] = lsum;

    part[wid][0][lane] = acc0;
    part[wid][1][lane] = acc1;
    part[wid][2][lane] = acc2;
    part[wid][3][lane] = acc3;
    __syncthreads();
    if (t < 16) invs[t] = 1.0f / (redsum[0][t] + redsum[1][t] + redsum[2][t] + redsum[3][t]);
    __syncthreads();

    // reduce 4 wave-partials; C mapping: col=lane&15, row=(lane>>4)*4+reg
    int c = t & 63, rg = t >> 6;
    int ls = rg * 16 + (c & 15), dt = c >> 4;
    float4v s = part[0][dt][ls] + part[1][dt][ls] + part[2][dt][ls] + part[3][dt][ls];
    const float* rl = root_list + ((size_t)b * DEPTH + ridx) * N;
#pragma unroll
    for (int reg = 0; reg < 4; ++reg) {
        int rr = rg * 4 + reg;
        if (rl[n0 + rr] > 0.f)
            h[((size_t)(b * N + n0 + rr)) * D + c] = s[reg] * invs[rr];
    }
}

// ---------------- pooling + BN-MLP + softmax, 1024 threads/batch ----------------
__global__ __launch_bounds__(1024) void k_pool(const float* __restrict__ h,
                       const float* __restrict__ root_list, const float* __restrict__ P,
                       const float* __restrict__ pW1, const float* __restrict__ pb1,
                       const float* __restrict__ g1, const float* __restrict__ be1,
                       const float* __restrict__ m1, const float* __restrict__ v1,
                       const float* __restrict__ pW2, const float* __restrict__ pb2,
                       const float* __restrict__ g2, const float* __restrict__ be2,
                       const float* __restrict__ m2, const float* __restrict__ v2,
                       const float* __restrict__ pW3, const float* __restrict__ pb3,
                       float* __restrict__ out) {
    int b = blockIdx.x, t = threadIdx.x, lane = t & 63, wid = t >> 6;  // 16 waves
    __shared__ float w[N];
    __shared__ float red[16];
    __shared__ float part[16][D];
    __shared__ float od[D];
    __shared__ float x1[128];
    __shared__ float x2[64];
    __shared__ float lg[2];

    const float* hb = h + (size_t)b * N * D;
    const float* rl = root_list + ((size_t)b * DEPTH + 1) * N;
    float pvl = P[lane];

    // dot phase: wave wid handles rows wid*64..+63, coalesced row loads
    for (int j = 0; j < 64; ++j) {
        int n = wid * 64 + j;
        float p = hb[(size_t)n * D + lane] * pvl;
#pragma unroll
        for (int o = 32; o > 0; o >>= 1) p += __shfl_xor(p, o);
        if (lane == 0) w[n] = (rl[n] > 0.f) ? fmaxf(p, 0.f) : -9e15f;
    }
    __syncthreads();

    float lmax = w[t];
#pragma unroll
    for (int o = 32; o > 0; o >>= 1) lmax = fmaxf(lmax, __shfl_xor(lmax, o));
    if (lane == 0) red[wid] = lmax;
    __syncthreads();
    float bmax = red[0];
#pragma unroll
    for (int k = 1; k < 16; ++k) bmax = fmaxf(bmax, red[k]);
    __syncthreads();

    float e = __expf(w[t] - bmax);
    w[t] = e;
    float lsumv = e;
#pragma unroll
    for (int o = 32; o > 0; o >>= 1) lsumv += __shfl_xor(lsumv, o);
    if (lane == 0) red[wid] = lsumv;
    __syncthreads();
    float bsum = 0.f;
#pragma unroll
    for (int k = 0; k < 16; ++k) bsum += red[k];
    float inv = 1.0f / bsum;

    float acc = 0.f;
    for (int n = wid * 64; n < wid * 64 + 64; ++n) acc += w[n] * hb[(size_t)n * D + lane];
    part[wid][lane] = acc;
    __syncthreads();
    if (t < D) {
        float s = 0.f;
#pragma unroll
        for (int k = 0; k < 16; ++k) s += part[k][t];
        od[t] = s * inv;
    }
    __syncthreads();

    if (t < 128) {
        float s = pb1[t];
#pragma unroll
        for (int k = 0; k < D; ++k) s += od[k] * pW1[k * 128 + t];
        s = (s - m1[t]) * rsqrtf(v1[t] + BN_EPS) * g1[t] + be1[t];
        x1[t] = fmaxf(s, 0.f);
    }
    __syncthreads();
    if (t < 64) {
        float s = pb2[t];
#pragma unroll
        for (int k = 0; k < 128; ++k) s += x1[k] * pW2[k * 64 + t];
        s = (s - m2[t]) * rsqrtf(v2[t] + BN_EPS) * g2[t] + be2[t];
        x2[t] = fmaxf(s, 0.f);
    }
    __syncthreads();
    if (t < 2) {
        float s = pb3[t];
#pragma unroll
        for (int k = 0; k < 64; ++k) s += x2[k] * pW3[k * 2 + t];
        lg[t] = fmaxf(s, 0.f);
    }
    __syncthreads();
    if (t < 2) {
        float mm = fmaxf(lg[0], lg[1]);
        float e0 = __expf(lg[0] - mm), e1 = __expf(lg[1] - mm);
        out[b * 2 + t] = ((t == 0) ? e0 : e1) / (e0 + e1);
    }
}

extern "C" void kernel_launch(void* const* d_in, const int* in_sizes, int n_in,
                              void* d_out, int out_size, void* d_ws, size_t ws_size,
                              hipStream_t stream) {
    const int*   adj = (const int*)d_in[0];
    const float* X   = (const float*)d_in[1];
    const float* rl  = (const float*)d_in[2];
    const float* W0  = (const float*)d_in[3];
    const float* Wl  = (const float*)d_in[4];
    const float* a1l = (const float*)d_in[5];
    const float* a2l = (const float*)d_in[6];
    const float* P   = (const float*)d_in[7];
    const float* pW1 = (const float*)d_in[8];
    const float* pb1 = (const float*)d_in[9];
    const float* g1  = (const float*)d_in[10];
    const float* be1 = (const float*)d_in[11];
    const float* m1  = (const float*)d_in[12];
    const float* v1  = (const float*)d_in[13];
    const float* pW2 = (const float*)d_in[14];
    const float* pb2 = (const float*)d_in[15];
    const float* g2  = (const float*)d_in[16];
    const float* be2 = (const float*)d_in[17];
    const float* m2  = (const float*)d_in[18];
    const float* v2  = (const float*)d_in[19];
    const float* pW3 = (const float*)d_in[20];
    const float* pb3 = (const float*)d_in[21];
    float* out = (float*)d_out;

    // ws layout: 10,616,832 B total — exactly the footprint proven in R3
    float*          h    = (float*)d_ws;                                   // 4MB
    unsigned short* hWhi = (unsigned short*)(h + (size_t)B * N * D);       // 2MB
    unsigned short* hWlo = hWhi + (size_t)B * N * D;                       // 2MB
    float*          t1   = (float*)(hWlo + (size_t)B * N * D);             // 64KB
    float*          t2   = t1 + B * N;                                     // 64KB
    unsigned long long* packA = (unsigned long long*)(t2 + B * N);         // 2MB

    k_pack<<<1024, 256, 0, stream>>>(adj, packA);
    k_h0<<<B * 64, 256, 0, stream>>>(X, W0, h);
    for (int i = 0; i < DEPTH - 1; ++i) {
        k_hw<<<B * 64, 256, 0, stream>>>(h, Wl + i * D * D, a1l + i * D, a2l + i * D,
                                         hWhi, hWlo, t1, t2);
        k_att<<<B * 64, 256, 0, stream>>>(hWhi, hWlo, t1, t2, packA, rl,
                                          DEPTH - 1 - i, h);
    }
    k_pool<<<B, 1024, 0, stream>>>(h, rl, P, pW1, pb1, g1, be1, m1, v1,
                                   pW2, pb2, g2, be2, m2, v2, pW3, pb3, out);
}

// Round 8
// 301.436 us; speedup vs baseline: 2.2942x; 1.0963x over previous
//
#include <hip/hip_runtime.h>
#include <hip/hip_bf16.h>
#include <math.h>

#define B 16
#define N 1024
#define F_IN 80
#define D 64
#define DEPTH 4
#define BN_EPS 1e-5f

typedef __attribute__((ext_vector_type(8))) short  short8v;
typedef __attribute__((ext_vector_type(4))) float  float4v;

union AFrag { unsigned int u[4]; short8v s; };

__device__ __forceinline__ unsigned short f2bf_rne(float x) {
    unsigned int u = __float_as_uint(x);
    unsigned int r = u + 0x7FFFu + ((u >> 16) & 1u);
    return (unsigned short)(r >> 16);
}
__device__ __forceinline__ float bf2f(unsigned short b) {
    return __uint_as_float(((unsigned int)b) << 16);
}

// ---------------- adj bit-pack: 64 int32 -> 1 u64 ----------------
__global__ void k_pack(const int* __restrict__ adj, unsigned long long* __restrict__ packA) {
    int gw   = (blockIdx.x * blockDim.x + threadIdx.x) >> 6;
    int lane = threadIdx.x & 63;
    for (int it = 0; it < 64; ++it) {
        size_t word = (size_t)gw * 64 + it;
        unsigned long long m = __ballot(adj[word * 64 + lane] > 0);
        if (lane == 0) packA[word] = m;
    }
}

// ---------------- h = relu(X @ W0), 16 rows/block ----------------
__global__ __launch_bounds__(256) void k_h0(const float* __restrict__ X,
                                            const float* __restrict__ W0,
                                            float* __restrict__ h) {
    int b = blockIdx.x >> 6, n0 = (blockIdx.x & 63) << 4;
    int t = threadIdx.x;
    __shared__ float w0s[F_IN * D];   // 20KB
    __shared__ float xs[16 * F_IN];   // 5KB
    for (int j = t; j < F_IN * D; j += 256) w0s[j] = W0[j];
    const float* xp = X + ((size_t)(b * N + n0)) * F_IN;
    for (int j = t; j < 16 * F_IN; j += 256) xs[j] = xp[j];
    __syncthreads();
    int d = t & 63, wid = t >> 6;
    float acc[4] = {0.f, 0.f, 0.f, 0.f};
    for (int f = 0; f < F_IN; ++f) {
        float wv = w0s[f * D + d];
#pragma unroll
        for (int j = 0; j < 4; ++j) acc[j] += xs[(wid * 4 + j) * F_IN + f] * wv;
    }
    float* hp = h + ((size_t)(b * N + n0 + wid * 4)) * D + d;
#pragma unroll
    for (int j = 0; j < 4; ++j) hp[(size_t)j * D] = fmaxf(acc[j], 0.f);
}

// ---------------- hW = relu(h@Wl) -> bf16 hi/lo planes in B-frag order; t1,t2 ----------------
// plane offset for value hW[m][c]: ((kb*4+dt)*64 + lb)*8 + i
//   kb=m>>5, i=m&7, lb=((m>>3)&3)*16 + (c&15), dt=c>>4
__global__ __launch_bounds__(256) void k_hw(const float* __restrict__ h,
                                            const float* __restrict__ Wl,
                                            const float* __restrict__ a1,
                                            const float* __restrict__ a2,
                                            unsigned short* __restrict__ hWhi,
                                            unsigned short* __restrict__ hWlo,
                                            float* __restrict__ t1,
                                            float* __restrict__ t2) {
    int b = blockIdx.x >> 6, n0 = (blockIdx.x & 63) << 4;
    int t = threadIdx.x;
    __shared__ float wls[D * D];   // 16KB
    __shared__ float hs[16 * D];   // 4KB
    for (int j = t; j < D * D; j += 256) wls[j] = Wl[j];
    const float* hp = h + ((size_t)(b * N + n0)) * D;
    for (int j = t; j < 16 * D; j += 256) hs[j] = hp[j];
    __syncthreads();
    int d = t & 63, wid = t >> 6;
    float acc[4] = {0.f, 0.f, 0.f, 0.f};
    for (int k = 0; k < D; ++k) {
        float wv = wls[k * D + d];
#pragma unroll
        for (int j = 0; j < 4; ++j) acc[j] += hs[(wid * 4 + j) * D + k] * wv;
    }
    float a1d = a1[d], a2d = a2[d];
    unsigned short* Hb = hWhi + (size_t)b * (N * D);
    unsigned short* Lb = hWlo + (size_t)b * (N * D);
#pragma unroll
    for (int j = 0; j < 4; ++j) {
        int m = n0 + wid * 4 + j;
        float v = fmaxf(acc[j], 0.f);
        unsigned short vh = f2bf_rne(v);
        unsigned short vl = f2bf_rne(v - bf2f(vh));
        int kb = m >> 5, i = m & 7;
        int lb = ((m >> 3) & 3) * 16 + (d & 15), dt = d >> 4;
        int off = ((kb * 4 + dt) * 64 + lb) * 8 + i;
        Hb[off] = vh; Lb[off] = vl;
        float p1 = v * a1d, p2 = v * a2d;
#pragma unroll
        for (int o = 32; o > 0; o >>= 1) {
            p1 += __shfl_down(p1, o);
            p2 += __shfl_down(p2, o);
        }
        if (d == 0) { t1[b * N + m] = p1; t2[b * N + m] = p2; }
    }
}

// ---------------- fused attention: 16 rows/block, w born in A-frag regs ----------------
__global__ __launch_bounds__(256, 4) void k_att(
    const unsigned short* __restrict__ hWhi, const unsigned short* __restrict__ hWlo,
    const float* __restrict__ t1, const float* __restrict__ t2,
    const unsigned long long* __restrict__ packA,
    const float* __restrict__ root_list, int ridx, float* __restrict__ h)
{
    int vb = (blockIdx.x & 7) * 128 + (blockIdx.x >> 3);   // XCD swizzle (1024 blocks)
    int b  = vb >> 6;
    int n0 = (vb & 63) << 4;
    int t = threadIdx.x, lane = t & 63, wid = t >> 6;

    __shared__ float t2s[N];               // 4KB
    __shared__ float redsum[4][16];
    __shared__ float invs[16];
    __shared__ float4v part[4][4][64];     // 16KB: [wid][dt][lane]

    ((float4v*)t2s)[t] = ((const float4v*)(t2 + b * N))[t];
    __syncthreads();

    int r  = lane & 15;
    int qg = wid * 4 + (lane >> 4);        // 0..15: global k-subgroup within a pass
    int n  = n0 + r;
    float t1v = t1[b * N + n];
    const unsigned long long* prow = packA + ((size_t)(b * N + n)) * 16;
    const short8v* BH = (const short8v*)(hWhi + (size_t)b * (N * D));
    const short8v* BL = (const short8v*)(hWlo + (size_t)b * (N * D));

    float4v acc0 = {0,0,0,0}, acc1 = {0,0,0,0}, acc2 = {0,0,0,0}, acc3 = {0,0,0,0};
    float lsum = 0.f;

#pragma unroll
    for (int p = 0; p < 8; ++p) {
        int kb = p * 4 + wid;              // this wave's 32-wide k-block
        int bi = (kb * 4) * 64 + lane;
        short8v bh0 = BH[bi], bh1 = BH[bi + 64], bh2 = BH[bi + 128], bh3 = BH[bi + 192];
        short8v bl0 = BL[bi], bl1 = BL[bi + 64], bl2 = BL[bi + 128], bl3 = BL[bi + 192];

        unsigned long long word = prow[p * 2 + (qg >> 3)];
        unsigned int mbyte = (unsigned int)(word >> ((qg & 7) * 8)) & 0xFFu;

        const float* t2p = t2s + p * 128 + qg * 8;
        float4v ta = ((const float4v*)t2p)[0];
        float4v tb = ((const float4v*)t2p)[1];

        float wv[8];
#pragma unroll
        for (int i = 0; i < 8; ++i) {
            float t2v = (i < 4) ? ta[i & 3] : tb[i & 3];
            float e = ((mbyte >> i) & 1u) ? fmaxf(t1v + t2v, 0.f) : 0.f;
            float w = __expf(e);
            wv[i] = w;
            lsum += w;
        }

        AFrag fh, fl;
#pragma unroll
        for (int i = 0; i < 4; ++i) {
            unsigned short h0 = f2bf_rne(wv[2 * i]);
            unsigned short h1 = f2bf_rne(wv[2 * i + 1]);
            unsigned short l0 = f2bf_rne(wv[2 * i] - bf2f(h0));
            unsigned short l1 = f2bf_rne(wv[2 * i + 1] - bf2f(h1));
            fh.u[i] = (unsigned int)h0 | ((unsigned int)h1 << 16);
            fl.u[i] = (unsigned int)l0 | ((unsigned int)l1 << 16);
        }

        acc0 = __builtin_amdgcn_mfma_f32_16x16x32_bf16(fh.s, bh0, acc0, 0, 0, 0);
        acc0 = __builtin_amdgcn_mfma_f32_16x16x32_bf16(fh.s, bl0, acc0, 0, 0, 0);
        acc0 = __builtin_amdgcn_mfma_f32_16x16x32_bf16(fl.s, bh0, acc0, 0, 0, 0);
        acc1 = __builtin_amdgcn_mfma_f32_16x16x32_bf16(fh.s, bh1, acc1, 0, 0, 0);
        acc1 = __builtin_amdgcn_mfma_f32_16x16x32_bf16(fh.s, bl1, acc1, 0, 0, 0);
        acc1 = __builtin_amdgcn_mfma_f32_16x16x32_bf16(fl.s, bh1, acc1, 0, 0, 0);
        acc2 = __builtin_amdgcn_mfma_f32_16x16x32_bf16(fh.s, bh2, acc2, 0, 0, 0);
        acc2 = __builtin_amdgcn_mfma_f32_16x16x32_bf16(fh.s, bl2, acc2, 0, 0, 0);
        acc2 = __builtin_amdgcn_mfma_f32_16x16x32_bf16(fl.s, bh2, acc2, 0, 0, 0);
        acc3 = __builtin_amdgcn_mfma_f32_16x16x32_bf16(fh.s, bh3, acc3, 0, 0, 0);
        acc3 = __builtin_amdgcn_mfma_f32_16x16x32_bf16(fh.s, bl3, acc3, 0, 0, 0);
        acc3 = __builtin_amdgcn_mfma_f32_16x16x32_bf16(fl.s, bh3, acc3, 0, 0, 0);
    }

    // per-row softmax denominators: lanes {l, l^16, l^32, l^48} share a row
    lsum += __shfl_xor(lsum, 16);
    lsum += __shfl_xor(lsum, 32);
    if (lane < 16) redsum[wid][lane] = lsum;

    part[wid][0][lane] = acc0;
    part[wid][1][lane] = acc1;
    part[wid][2][lane] = acc2;
    part[wid][3][lane] = acc3;
    __syncthreads();
    if (t < 16) invs[t] = 1.0f / (redsum[0][t] + redsum[1][t] + redsum[2][t] + redsum[3][t]);
    __syncthreads();

    // reduce 4 wave-partials; C mapping: col=lane&15, row=(lane>>4)*4+reg
    int c = t & 63, rg = t >> 6;
    int ls = rg * 16 + (c & 15), dt = c >> 4;
    float4v s = part[0][dt][ls] + part[1][dt][ls] + part[2][dt][ls] + part[3][dt][ls];
    const float* rl = root_list + ((size_t)b * DEPTH + ridx) * N;
#pragma unroll
    for (int reg = 0; reg < 4; ++reg) {
        int rr = rg * 4 + reg;
        if (rl[n0 + rr] > 0.f)
            h[((size_t)(b * N + n0 + rr)) * D + c] = s[reg] * invs[rr];
    }
}

// ---------------- pooling dot: w[b][n] = root>0 ? relu(h.P) : -9e15 ----------------
__global__ __launch_bounds__(256) void k_dotw(const float* __restrict__ h,
                                              const float* __restrict__ root_list,
                                              const float* __restrict__ P,
                                              float* __restrict__ wg) {
    int b = blockIdx.x >> 4, n0 = (blockIdx.x & 15) << 6;
    int t = threadIdx.x;
    int r = n0 + (t >> 2), sub = t & 3;
    const float4* hp = (const float4*)(h + ((size_t)(b * N + r)) * D + sub * 16);
    const float4* pp = (const float4*)(P + sub * 16);
    float s = 0.f;
#pragma unroll
    for (int i = 0; i < 4; ++i) {
        float4 hv = hp[i], pv = pp[i];
        s += hv.x * pv.x + hv.y * pv.y + hv.z * pv.z + hv.w * pv.w;
    }
    s += __shfl_xor(s, 1);
    s += __shfl_xor(s, 2);
    if (sub == 0) {
        float rv = root_list[((size_t)b * DEPTH + 1) * N + r];
        wg[b * N + r] = (rv > 0.f) ? fmaxf(s, 0.f) : -9e15f;
    }
}

// ---------------- softmax + weighted sum + BN-MLP, 1024 threads/batch ----------------
__global__ __launch_bounds__(1024) void k_pool2(const float* __restrict__ h,
                       const float* __restrict__ wg,
                       const float* __restrict__ pW1, const float* __restrict__ pb1,
                       const float* __restrict__ g1, const float* __restrict__ be1,
                       const float* __restrict__ m1, const float* __restrict__ v1,
                       const float* __restrict__ pW2, const float* __restrict__ pb2,
                       const float* __restrict__ g2, const float* __restrict__ be2,
                       const float* __restrict__ m2, const float* __restrict__ v2,
                       const float* __restrict__ pW3, const float* __restrict__ pb3,
                       float* __restrict__ out) {
    int b = blockIdx.x, t = threadIdx.x, lane = t & 63, wid = t >> 6;  // 16 waves
    __shared__ float ws[N];
    __shared__ float red[16];
    __shared__ float part[16][D];
    __shared__ float od[D];
    __shared__ float x1[128];
    __shared__ float x2[64];
    __shared__ float lg[2];

    const float* hb = h + (size_t)b * N * D;
    float sc = wg[b * N + t];

    float lmax = sc;
#pragma unroll
    for (int o = 32; o > 0; o >>= 1) lmax = fmaxf(lmax, __shfl_xor(lmax, o));
    if (lane == 0) red[wid] = lmax;
    __syncthreads();
    float bmax = red[0];
#pragma unroll
    for (int k = 1; k < 16; ++k) bmax = fmaxf(bmax, red[k]);
    __syncthreads();

    float e = __expf(sc - bmax);
    ws[t] = e;
    float lsumv = e;
#pragma unroll
    for (int o = 32; o > 0; o >>= 1) lsumv += __shfl_xor(lsumv, o);
    if (lane == 0) red[wid] = lsumv;
    __syncthreads();
    float bsum = 0.f;
#pragma unroll
    for (int k = 0; k < 16; ++k) bsum += red[k];
    float inv = 1.0f / bsum;

    float acc = 0.f;
    for (int n = wid * 64; n < wid * 64 + 64; ++n) acc += ws[n] * hb[(size_t)n * D + lane];
    part[wid][lane] = acc;
    __syncthreads();
    if (t < D) {
        float s = 0.f;
#pragma unroll
        for (int k = 0; k < 16; ++k) s += part[k][t];
        od[t] = s * inv;
    }
    __syncthreads();

    if (t < 128) {
        float s = pb1[t];
#pragma unroll
        for (int k = 0; k < D; ++k) s += od[k] * pW1[k * 128 + t];
        s = (s - m1[t]) * rsqrtf(v1[t] + BN_EPS) * g1[t] + be1[t];
        x1[t] = fmaxf(s, 0.f);
    }
    __syncthreads();
    if (t < 64) {
        float s = pb2[t];
#pragma unroll
        for (int k = 0; k < 128; ++k) s += x1[k] * pW2[k * 64 + t];
        s = (s - m2[t]) * rsqrtf(v2[t] + BN_EPS) * g2[t] + be2[t];
        x2[t] = fmaxf(s, 0.f);
    }
    __syncthreads();
    if (t < 2) {
        float s = pb3[t];
#pragma unroll
        for (int k = 0; k < 64; ++k) s += x2[k] * pW3[k * 2 + t];
        lg[t] = fmaxf(s, 0.f);
    }
    __syncthreads();
    if (t < 2) {
        float mm = fmaxf(lg[0], lg[1]);
        float e0 = __expf(lg[0] - mm), e1 = __expf(lg[1] - mm);
        out[b * 2 + t] = ((t == 0) ? e0 : e1) / (e0 + e1);
    }
}

extern "C" void kernel_launch(void* const* d_in, const int* in_sizes, int n_in,
                              void* d_out, int out_size, void* d_ws, size_t ws_size,
                              hipStream_t stream) {
    const int*   adj = (const int*)d_in[0];
    const float* X   = (const float*)d_in[1];
    const float* rl  = (const float*)d_in[2];
    const float* W0  = (const float*)d_in[3];
    const float* Wl  = (const float*)d_in[4];
    const float* a1l = (const float*)d_in[5];
    const float* a2l = (const float*)d_in[6];
    const float* P   = (const float*)d_in[7];
    const float* pW1 = (const float*)d_in[8];
    const float* pb1 = (const float*)d_in[9];
    const float* g1  = (const float*)d_in[10];
    const float* be1 = (const float*)d_in[11];
    const float* m1  = (const float*)d_in[12];
    const float* v1  = (const float*)d_in[13];
    const float* pW2 = (const float*)d_in[14];
    const float* pb2 = (const float*)d_in[15];
    const float* g2  = (const float*)d_in[16];
    const float* be2 = (const float*)d_in[17];
    const float* m2  = (const float*)d_in[18];
    const float* v2  = (const float*)d_in[19];
    const float* pW3 = (const float*)d_in[20];
    const float* pb3 = (const float*)d_in[21];
    float* out = (float*)d_out;

    // ws layout: 10,616,832 B total — exactly the footprint proven in R3/R7
    float*          h    = (float*)d_ws;                                   // 4MB
    unsigned short* hWhi = (unsigned short*)(h + (size_t)B * N * D);       // 2MB
    unsigned short* hWlo = hWhi + (size_t)B * N * D;                       // 2MB
    float*          t1   = (float*)(hWlo + (size_t)B * N * D);             // 64KB
    float*          t2   = t1 + B * N;                                     // 64KB
    unsigned long long* packA = (unsigned long long*)(t2 + B * N);         // 2MB
    float*          wg   = t1;   // t1 dead after layer loop; reuse for pooling scores

    k_pack<<<1024, 256, 0, stream>>>(adj, packA);
    k_h0<<<B * 64, 256, 0, stream>>>(X, W0, h);
    for (int i = 0; i < DEPTH - 1; ++i) {
        k_hw<<<B * 64, 256, 0, stream>>>(h, Wl + i * D * D, a1l + i * D, a2l + i * D,
                                         hWhi, hWlo, t1, t2);
        k_att<<<B * 64, 256, 0, stream>>>(hWhi, hWlo, t1, t2, packA, rl,
                                          DEPTH - 1 - i, h);
    }
    k_dotw<<<B * 16, 256, 0, stream>>>(h, rl, P, wg);
    k_pool2<<<B, 1024, 0, stream>>>(h, wg, pW1, pb1, g1, be1, m1, v1,
                                    pW2, pb2, g2, be2, m2, v2, pW3, pb3, out);
}

// Round 10
// 267.163 us; speedup vs baseline: 2.5885x; 1.1283x over previous
//
#include <hip/hip_runtime.h>
#include <hip/hip_bf16.h>
#include <math.h>

#define B 16
#define N 1024
#define F_IN 80
#define D 64
#define DEPTH 4
#define BN_EPS 1e-5f

typedef __attribute__((ext_vector_type(8))) short  short8v;
typedef __attribute__((ext_vector_type(4))) float  float4v;

union AFrag { unsigned int u[4]; short8v s; };

__device__ __forceinline__ unsigned short f2bf_rne(float x) {
    unsigned int u = __float_as_uint(x);
    unsigned int r = u + 0x7FFFu + ((u >> 16) & 1u);
    return (unsigned short)(r >> 16);
}
__device__ __forceinline__ float bf2f(unsigned short b) {
    return __uint_as_float(((unsigned int)b) << 16);
}

// ---------------- adj bit-pack: each thread 16 ints -> one u16 store ----------------
// word w covers adj ints [w*64, w*64+64); thread gid covers ints [gid*16, gid*16+16)
// and stores bits [ (gid&3)*16, +16 ) of word gid>>2 via little-endian u16 layout.
__global__ __launch_bounds__(256) void k_pack(const int* __restrict__ adj,
                                              unsigned short* __restrict__ packS) {
    int gid = blockIdx.x * 256 + threadIdx.x;      // 0 .. B*N*N/16-1
    const int4* ap = (const int4*)adj + (size_t)gid * 4;
    unsigned int m = 0;
#pragma unroll
    for (int i = 0; i < 4; ++i) {
        int4 v = ap[i];
        m |= (unsigned int)(v.x > 0) << (i * 4 + 0);
        m |= (unsigned int)(v.y > 0) << (i * 4 + 1);
        m |= (unsigned int)(v.z > 0) << (i * 4 + 2);
        m |= (unsigned int)(v.w > 0) << (i * 4 + 3);
    }
    packS[gid] = (unsigned short)m;
}

// ---------------- h = relu(X @ W0), 16 rows/block ----------------
__global__ __launch_bounds__(256) void k_h0(const float* __restrict__ X,
                                            const float* __restrict__ W0,
                                            float* __restrict__ h) {
    int b = blockIdx.x >> 6, n0 = (blockIdx.x & 63) << 4;
    int t = threadIdx.x;
    __shared__ float w0s[F_IN * D];   // 20KB
    __shared__ float xs[16 * F_IN];   // 5KB
    for (int j = t; j < F_IN * D; j += 256) w0s[j] = W0[j];
    const float* xp = X + ((size_t)(b * N + n0)) * F_IN;
    for (int j = t; j < 16 * F_IN; j += 256) xs[j] = xp[j];
    __syncthreads();
    int d = t & 63, wid = t >> 6;
    float acc[4] = {0.f, 0.f, 0.f, 0.f};
    for (int f = 0; f < F_IN; ++f) {
        float wv = w0s[f * D + d];
#pragma unroll
        for (int j = 0; j < 4; ++j) acc[j] += xs[(wid * 4 + j) * F_IN + f] * wv;
    }
    float* hp = h + ((size_t)(b * N + n0 + wid * 4)) * D + d;
#pragma unroll
    for (int j = 0; j < 4; ++j) hp[(size_t)j * D] = fmaxf(acc[j], 0.f);
}

// ---------------- hW = relu(h@Wl) -> bf16 hi/lo planes in B-frag order; t1,t2 ----------------
// plane offset for value hW[m][c]: ((kb*4+dt)*64 + lb)*8 + i
//   kb=m>>5, i=m&7, lb=((m>>3)&3)*16 + (c&15), dt=c>>4
__global__ __launch_bounds__(256) void k_hw(const float* __restrict__ h,
                                            const float* __restrict__ Wl,
                                            const float* __restrict__ a1,
                                            const float* __restrict__ a2,
                                            unsigned short* __restrict__ hWhi,
                                            unsigned short* __restrict__ hWlo,
                                            float* __restrict__ t1,
                                            float* __restrict__ t2) {
    int b = blockIdx.x >> 6, n0 = (blockIdx.x & 63) << 4;
    int t = threadIdx.x;
    __shared__ float wls[D * D];   // 16KB
    __shared__ float hs[16 * D];   // 4KB
    for (int j = t; j < D * D; j += 256) wls[j] = Wl[j];
    const float* hp = h + ((size_t)(b * N + n0)) * D;
    for (int j = t; j < 16 * D; j += 256) hs[j] = hp[j];
    __syncthreads();
    int d = t & 63, wid = t >> 6;
    float acc[4] = {0.f, 0.f, 0.f, 0.f};
    for (int k = 0; k < D; ++k) {
        float wv = wls[k * D + d];
#pragma unroll
        for (int j = 0; j < 4; ++j) acc[j] += hs[(wid * 4 + j) * D + k] * wv;
    }
    float a1d = a1[d], a2d = a2[d];
    unsigned short* Hb = hWhi + (size_t)b * (N * D);
    unsigned short* Lb = hWlo + (size_t)b * (N * D);
#pragma unroll
    for (int j = 0; j < 4; ++j) {
        int m = n0 + wid * 4 + j;
        float v = fmaxf(acc[j], 0.f);
        unsigned short vh = f2bf_rne(v);
        unsigned short vl = f2bf_rne(v - bf2f(vh));
        int kb = m >> 5, i = m & 7;
        int lb = ((m >> 3) & 3) * 16 + (d & 15), dt = d >> 4;
        int off = ((kb * 4 + dt) * 64 + lb) * 8 + i;
        Hb[off] = vh; Lb[off] = vl;
        float p1 = v * a1d, p2 = v * a2d;
#pragma unroll
        for (int o = 32; o > 0; o >>= 1) {
            p1 += __shfl_down(p1, o);
            p2 += __shfl_down(p2, o);
        }
        if (d == 0) { t1[b * N + m] = p1; t2[b * N + m] = p2; }
    }
}

// ---------------- fused attention: 16 rows/block, w born in A-frag regs ----------------
__global__ __launch_bounds__(256, 4) void k_att(
    const unsigned short* __restrict__ hWhi, const unsigned short* __restrict__ hWlo,
    const float* __restrict__ t1, const float* __restrict__ t2,
    const unsigned long long* __restrict__ packA,
    const float* __restrict__ root_list, int ridx, float* __restrict__ h)
{
    int vb = (blockIdx.x & 7) * 128 + (blockIdx.x >> 3);   // XCD swizzle (1024 blocks)
    int b  = vb >> 6;
    int n0 = (vb & 63) << 4;
    int t = threadIdx.x, lane = t & 63, wid = t >> 6;

    __shared__ float t2s[N];               // 4KB
    __shared__ float redsum[4][16];
    __shared__ float invs[16];
    __shared__ float4v part[4][4][64];     // 16KB: [wid][dt][lane]

    ((float4v*)t2s)[t] = ((const float4v*)(t2 + b * N))[t];
    __syncthreads();

    int r  = lane & 15;
    int qg = wid * 4 + (lane >> 4);        // 0..15: global k-subgroup within a pass
    int n  = n0 + r;
    float t1v = t1[b * N + n];
    const unsigned long long* prow = packA + ((size_t)(b * N + n)) * 16;
    const short8v* BH = (const short8v*)(hWhi + (size_t)b * (N * D));
    const short8v* BL = (const short8v*)(hWlo + (size_t)b * (N * D));

    float4v acc0 = {0,0,0,0}, acc1 = {0,0,0,0}, acc2 = {0,0,0,0}, acc3 = {0,0,0,0};
    float lsum = 0.f;

#pragma unroll
    for (int p = 0; p < 8; ++p) {
        int kb = p * 4 + wid;              // this wave's 32-wide k-block
        int bi = (kb * 4) * 64 + lane;
        short8v bh0 = BH[bi], bh1 = BH[bi + 64], bh2 = BH[bi + 128], bh3 = BH[bi + 192];
        short8v bl0 = BL[bi], bl1 = BL[bi + 64], bl2 = BL[bi + 128], bl3 = BL[bi + 192];

        unsigned long long word = prow[p * 2 + (qg >> 3)];
        unsigned int mbyte = (unsigned int)(word >> ((qg & 7) * 8)) & 0xFFu;

        const float* t2p = t2s + p * 128 + qg * 8;
        float4v ta = ((const float4v*)t2p)[0];
        float4v tb = ((const float4v*)t2p)[1];

        float wv[8];
#pragma unroll
        for (int i = 0; i < 8; ++i) {
            float t2v = (i < 4) ? ta[i & 3] : tb[i & 3];
            float e = ((mbyte >> i) & 1u) ? fmaxf(t1v + t2v, 0.f) : 0.f;
            float w = __expf(e);
            wv[i] = w;
            lsum += w;
        }

        AFrag fh, fl;
#pragma unroll
        for (int i = 0; i < 4; ++i) {
            unsigned short h0 = f2bf_rne(wv[2 * i]);
            unsigned short h1 = f2bf_rne(wv[2 * i + 1]);
            unsigned short l0 = f2bf_rne(wv[2 * i] - bf2f(h0));
            unsigned short l1 = f2bf_rne(wv[2 * i + 1] - bf2f(h1));
            fh.u[i] = (unsigned int)h0 | ((unsigned int)h1 << 16);
            fl.u[i] = (unsigned int)l0 | ((unsigned int)l1 << 16);
        }

        acc0 = __builtin_amdgcn_mfma_f32_16x16x32_bf16(fh.s, bh0, acc0, 0, 0, 0);
        acc0 = __builtin_amdgcn_mfma_f32_16x16x32_bf16(fh.s, bl0, acc0, 0, 0, 0);
        acc0 = __builtin_amdgcn_mfma_f32_16x16x32_bf16(fl.s, bh0, acc0, 0, 0, 0);
        acc1 = __builtin_amdgcn_mfma_f32_16x16x32_bf16(fh.s, bh1, acc1, 0, 0, 0);
        acc1 = __builtin_amdgcn_mfma_f32_16x16x32_bf16(fh.s, bl1, acc1, 0, 0, 0);
        acc1 = __builtin_amdgcn_mfma_f32_16x16x32_bf16(fl.s, bh1, acc1, 0, 0, 0);
        acc2 = __builtin_amdgcn_mfma_f32_16x16x32_bf16(fh.s, bh2, acc2, 0, 0, 0);
        acc2 = __builtin_amdgcn_mfma_f32_16x16x32_bf16(fh.s, bl2, acc2, 0, 0, 0);
        acc2 = __builtin_amdgcn_mfma_f32_16x16x32_bf16(fl.s, bh2, acc2, 0, 0, 0);
        acc3 = __builtin_amdgcn_mfma_f32_16x16x32_bf16(fh.s, bh3, acc3, 0, 0, 0);
        acc3 = __builtin_amdgcn_mfma_f32_16x16x32_bf16(fh.s, bl3, acc3, 0, 0, 0);
        acc3 = __builtin_amdgcn_mfma_f32_16x16x32_bf16(fl.s, bh3, acc3, 0, 0, 0);
    }

    // per-row softmax denominators: lanes {l, l^16, l^32, l^48} share a row
    lsum += __shfl_xor(lsum, 16);
    lsum += __shfl_xor(lsum, 32);
    if (lane < 16) redsum[wid][lane] = lsum;

    part[wid][0][lane] = acc0;
    part[wid][1][lane] = acc1;
    part[wid][2][lane] = acc2;
    part[wid][3][lane] = acc3;
    __syncthreads();
    if (t < 16) invs[t] = 1.0f / (redsum[0][t] + redsum[1][t] + redsum[2][t] + redsum[3][t]);
    __syncthreads();

    // reduce 4 wave-partials; C mapping: col=lane&15, row=(lane>>4)*4+reg
    int c = t & 63, rg = t >> 6;
    int ls = rg * 16 + (c & 15), dt = c >> 4;
    float4v s = part[0][dt][ls] + part[1][dt][ls] + part[2][dt][ls] + part[3][dt][ls];
    const float* rl = root_list + ((size_t)b * DEPTH + ridx) * N;
#pragma unroll
    for (int reg = 0; reg < 4; ++reg) {
        int rr = rg * 4 + reg;
        if (rl[n0 + rr] > 0.f)
            h[((size_t)(b * N + n0 + rr)) * D + c] = s[reg] * invs[rr];
    }
}

// ---------------- pooling dot: w[b][n] = root>0 ? relu(h.P) : -9e15 ----------------
__global__ __launch_bounds__(256) void k_dotw(const float* __restrict__ h,
                                              const float* __restrict__ root_list,
                                              const float* __restrict__ P,
                                              float* __restrict__ wg) {
    int b = blockIdx.x >> 4, n0 = (blockIdx.x & 15) << 6;
    int t = threadIdx.x;
    int r = n0 + (t >> 2), sub = t & 3;
    const float4* hp = (const float4*)(h + ((size_t)(b * N + r)) * D + sub * 16);
    const float4* pp = (const float4*)(P + sub * 16);
    float s = 0.f;
#pragma unroll
    for (int i = 0; i < 4; ++i) {
        float4 hv = hp[i], pv = pp[i];
        s += hv.x * pv.x + hv.y * pv.y + hv.z * pv.z + hv.w * pv.w;
    }
    s += __shfl_xor(s, 1);
    s += __shfl_xor(s, 2);
    if (sub == 0) {
        float rv = root_list[((size_t)b * DEPTH + 1) * N + r];
        wg[b * N + r] = (rv > 0.f) ? fmaxf(s, 0.f) : -9e15f;
    }
}

// ---------------- softmax + weighted sum + BN-MLP, 1024 threads/batch ----------------
__global__ __launch_bounds__(1024) void k_pool2(const float* __restrict__ h,
                       const float* __restrict__ wg,
                       const float* __restrict__ pW1, const float* __restrict__ pb1,
                       const float* __restrict__ g1, const float* __restrict__ be1,
                       const float* __restrict__ m1, const float* __restrict__ v1,
                       const float* __restrict__ pW2, const float* __restrict__ pb2,
                       const float* __restrict__ g2, const float* __restrict__ be2,
                       const float* __restrict__ m2, const float* __restrict__ v2,
                       const float* __restrict__ pW3, const float* __restrict__ pb3,
                       float* __restrict__ out) {
    int b = blockIdx.x, t = threadIdx.x, lane = t & 63, wid = t >> 6;  // 16 waves
    __shared__ float ws[N];
    __shared__ float red[16];
    __shared__ float part[16][D];
    __shared__ float od[D];
    __shared__ float x1[128];
    __shared__ float x2[64];
    __shared__ float lg[2];

    const float* hb = h + (size_t)b * N * D;
    float sc = wg[b * N + t];

    float lmax = sc;
#pragma unroll
    for (int o = 32; o > 0; o >>= 1) lmax = fmaxf(lmax, __shfl_xor(lmax, o));
    if (lane == 0) red[wid] = lmax;
    __syncthreads();
    float bmax = red[0];
#pragma unroll
    for (int k = 1; k < 16; ++k) bmax = fmaxf(bmax, red[k]);
    __syncthreads();

    float e = __expf(sc - bmax);
    ws[t] = e;
    float lsumv = e;
#pragma unroll
    for (int o = 32; o > 0; o >>= 1) lsumv += __shfl_xor(lsumv, o);
    if (lane == 0) red[wid] = lsumv;
    __syncthreads();
    float bsum = 0.f;
#pragma unroll
    for (int k = 0; k < 16; ++k) bsum += red[k];
    float inv = 1.0f / bsum;

    float acc = 0.f;
    for (int n = wid * 64; n < wid * 64 + 64; ++n) acc += ws[n] * hb[(size_t)n * D + lane];
    part[wid][lane] = acc;
    __syncthreads();
    if (t < D) {
        float s = 0.f;
#pragma unroll
        for (int k = 0; k < 16; ++k) s += part[k][t];
        od[t] = s * inv;
    }
    __syncthreads();

    if (t < 128) {
        float s = pb1[t];
#pragma unroll
        for (int k = 0; k < D; ++k) s += od[k] * pW1[k * 128 + t];
        s = (s - m1[t]) * rsqrtf(v1[t] + BN_EPS) * g1[t] + be1[t];
        x1[t] = fmaxf(s, 0.f);
    }
    __syncthreads();
    if (t < 64) {
        float s = pb2[t];
#pragma unroll
        for (int k = 0; k < 128; ++k) s += x1[k] * pW2[k * 64 + t];
        s = (s - m2[t]) * rsqrtf(v2[t] + BN_EPS) * g2[t] + be2[t];
        x2[t] = fmaxf(s, 0.f);
    }
    __syncthreads();
    if (t < 2) {
        float s = pb3[t];
#pragma unroll
        for (int k = 0; k < 64; ++k) s += x2[k] * pW3[k * 2 + t];
        lg[t] = fmaxf(s, 0.f);
    }
    __syncthreads();
    if (t < 2) {
        float mm = fmaxf(lg[0], lg[1]);
        float e0 = __expf(lg[0] - mm), e1 = __expf(lg[1] - mm);
        out[b * 2 + t] = ((t == 0) ? e0 : e1) / (e0 + e1);
    }
}

extern "C" void kernel_launch(void* const* d_in, const int* in_sizes, int n_in,
                              void* d_out, int out_size, void* d_ws, size_t ws_size,
                              hipStream_t stream) {
    const int*   adj = (const int*)d_in[0];
    const float* X   = (const float*)d_in[1];
    const float* rl  = (const float*)d_in[2];
    const float* W0  = (const float*)d_in[3];
    const float* Wl  = (const float*)d_in[4];
    const float* a1l = (const float*)d_in[5];
    const float* a2l = (const float*)d_in[6];
    const float* P   = (const float*)d_in[7];
    const float* pW1 = (const float*)d_in[8];
    const float* pb1 = (const float*)d_in[9];
    const float* g1  = (const float*)d_in[10];
    const float* be1 = (const float*)d_in[11];
    const float* m1  = (const float*)d_in[12];
    const float* v1  = (const float*)d_in[13];
    const float* pW2 = (const float*)d_in[14];
    const float* pb2 = (const float*)d_in[15];
    const float* g2  = (const float*)d_in[16];
    const float* be2 = (const float*)d_in[17];
    const float* m2  = (const float*)d_in[18];
    const float* v2  = (const float*)d_in[19];
    const float* pW3 = (const float*)d_in[20];
    const float* pb3 = (const float*)d_in[21];
    float* out = (float*)d_out;

    // ws layout: 10,616,832 B total — exactly the footprint proven in R3/R7/R8
    float*          h    = (float*)d_ws;                                   // 4MB
    unsigned short* hWhi = (unsigned short*)(h + (size_t)B * N * D);       // 2MB
    unsigned short* hWlo = hWhi + (size_t)B * N * D;                       // 2MB
    float*          t1   = (float*)(hWlo + (size_t)B * N * D);             // 64KB
    float*          t2   = t1 + B * N;                                     // 64KB
    unsigned long long* packA = (unsigned long long*)(t2 + B * N);         // 2MB
    float*          wg   = t1;   // t1 dead after layer loop; reuse for pooling scores

    k_pack<<<B * N * N / 16 / 256, 256, 0, stream>>>(adj, (unsigned short*)packA);
    k_h0<<<B * 64, 256, 0, stream>>>(X, W0, h);
    for (int i = 0; i < DEPTH - 1; ++i) {
        k_hw<<<B * 64, 256, 0, stream>>>(h, Wl + i * D * D, a1l + i * D, a2l + i * D,
                                         hWhi, hWlo, t1, t2);
        k_att<<<B * 64, 256, 0, stream>>>(hWhi, hWlo, t1, t2, packA, rl,
                                          DEPTH - 1 - i, h);
    }
    k_dotw<<<B * 16, 256, 0, stream>>>(h, rl, P, wg);
    k_pool2<<<B, 1024, 0, stream>>>(h, wg, pW1, pb1, g1, be1, m1, v1,
                                    pW2, pb2, g2, be2, m2, v2, pW3, pb3, out);
}

// Round 11
// 226.786 us; speedup vs baseline: 3.0494x; 1.1780x over previous
//
#include <hip/hip_runtime.h>
#include <hip/hip_bf16.h>
#include <math.h>

#define B 16
#define N 1024
#define F_IN 80
#define D 64
#define DEPTH 4
#define BN_EPS 1e-5f

typedef __attribute__((ext_vector_type(8))) short  short8v;
typedef __attribute__((ext_vector_type(4))) float  float4v;

union AFrag { unsigned int u[4]; short8v s; };

__device__ __forceinline__ unsigned short f2bf_rne(float x) {
    unsigned int u = __float_as_uint(x);
    unsigned int r = u + 0x7FFFu + ((u >> 16) & 1u);
    return (unsigned short)(r >> 16);
}
__device__ __forceinline__ float bf2f(unsigned short b) {
    return __uint_as_float(((unsigned int)b) << 16);
}
// trunc-split a pair of positives into packed bf16 hi / residual-lo words.
// |w - (hi+lo)| <= 2^-17 * w  (hi trunc 2^-8, residual trunc 2^-9 of 2^-8)
__device__ __forceinline__ void split_pair(float w0, float w1,
                                           unsigned int& hi, unsigned int& lo) {
    unsigned int u0 = __float_as_uint(w0), u1 = __float_as_uint(w1);
    unsigned int h0 = u0 & 0xFFFF0000u,   h1 = u1 & 0xFFFF0000u;
    hi = (h0 >> 16) | h1;
    float r0 = w0 - __uint_as_float(h0);
    float r1 = w1 - __uint_as_float(h1);
    lo = (__float_as_uint(r0) >> 16) | (__float_as_uint(r1) & 0xFFFF0000u);
}

// ---------------- adj bit-pack: each thread 16 ints -> one u16 store ----------------
__global__ __launch_bounds__(256) void k_pack(const int* __restrict__ adj,
                                              unsigned short* __restrict__ packS) {
    int gid = blockIdx.x * 256 + threadIdx.x;      // 0 .. B*N*N/16-1
    const int4* ap = (const int4*)adj + (size_t)gid * 4;
    unsigned int m = 0;
#pragma unroll
    for (int i = 0; i < 4; ++i) {
        int4 v = ap[i];
        m |= (unsigned int)(v.x > 0) << (i * 4 + 0);
        m |= (unsigned int)(v.y > 0) << (i * 4 + 1);
        m |= (unsigned int)(v.z > 0) << (i * 4 + 2);
        m |= (unsigned int)(v.w > 0) << (i * 4 + 3);
    }
    packS[gid] = (unsigned short)m;
}

// ---------------- h = relu(X @ W0), 16 rows/block ----------------
__global__ __launch_bounds__(256) void k_h0(const float* __restrict__ X,
                                            const float* __restrict__ W0,
                                            float* __restrict__ h) {
    int b = blockIdx.x >> 6, n0 = (blockIdx.x & 63) << 4;
    int t = threadIdx.x;
    __shared__ float w0s[F_IN * D];   // 20KB
    __shared__ float xs[16 * F_IN];   // 5KB
    for (int j = t; j < F_IN * D / 4; j += 256)
        ((float4*)w0s)[j] = ((const float4*)W0)[j];
    const float* xp = X + ((size_t)(b * N + n0)) * F_IN;
    for (int j = t; j < 16 * F_IN / 4; j += 256)
        ((float4*)xs)[j] = ((const float4*)xp)[j];
    __syncthreads();
    int d = t & 63, wid = t >> 6;
    float acc[4] = {0.f, 0.f, 0.f, 0.f};
    for (int f = 0; f < F_IN; ++f) {
        float wv = w0s[f * D + d];
#pragma unroll
        for (int j = 0; j < 4; ++j) acc[j] += xs[(wid * 4 + j) * F_IN + f] * wv;
    }
    float* hp = h + ((size_t)(b * N + n0 + wid * 4)) * D + d;
#pragma unroll
    for (int j = 0; j < 4; ++j) hp[(size_t)j * D] = fmaxf(acc[j], 0.f);
}

// ---------------- hW = relu(h@Wl) -> bf16 hi/lo planes in B-frag order; t1,t2 ----------------
// plane offset for value hW[m][c]: ((kb*4+dt)*64 + lb)*8 + i
//   kb=m>>5, i=m&7, lb=((m>>3)&3)*16 + (c&15), dt=c>>4
// Per thread the 4 j-offsets are consecutive (i = i0..i0+3, same kb/lb) -> one 8B store/plane.
__global__ __launch_bounds__(256) void k_hw(const float* __restrict__ h,
                                            const float* __restrict__ Wl,
                                            const float* __restrict__ a1,
                                            const float* __restrict__ a2,
                                            unsigned short* __restrict__ hWhi,
                                            unsigned short* __restrict__ hWlo,
                                            float* __restrict__ t1,
                                            float* __restrict__ t2) {
    int b = blockIdx.x >> 6, n0 = (blockIdx.x & 63) << 4;
    int t = threadIdx.x;
    __shared__ float wls[D * D];   // 16KB
    __shared__ float hs[16 * D];   // 4KB
    for (int j = t; j < D * D / 4; j += 256)
        ((float4*)wls)[j] = ((const float4*)Wl)[j];
    const float* hp = h + ((size_t)(b * N + n0)) * D;
    if (t < 16 * D / 4) ((float4*)hs)[t] = ((const float4*)hp)[t];
    __syncthreads();
    int d = t & 63, wid = t >> 6;
    float acc[4] = {0.f, 0.f, 0.f, 0.f};
    for (int k = 0; k < D; ++k) {
        float wv = wls[k * D + d];
#pragma unroll
        for (int j = 0; j < 4; ++j) acc[j] += hs[(wid * 4 + j) * D + k] * wv;
    }
    float a1d = a1[d], a2d = a2[d];

    float v[4];
    unsigned short vh[4], vl[4];
#pragma unroll
    for (int j = 0; j < 4; ++j) {
        v[j] = fmaxf(acc[j], 0.f);
        vh[j] = f2bf_rne(v[j]);
        vl[j] = f2bf_rne(v[j] - bf2f(vh[j]));
    }
    // vectorized store: j=0..3 are consecutive u16 slots
    {
        int m0 = n0 + wid * 4;
        int kb = m0 >> 5, i0 = m0 & 7;
        int lb = ((m0 >> 3) & 3) * 16 + (d & 15), dt = d >> 4;
        size_t off = ((size_t)b * (N * D)) + ((kb * 4 + dt) * 64 + lb) * 8 + i0;
        uint2 hpack, lpack;
        hpack.x = (unsigned int)vh[0] | ((unsigned int)vh[1] << 16);
        hpack.y = (unsigned int)vh[2] | ((unsigned int)vh[3] << 16);
        lpack.x = (unsigned int)vl[0] | ((unsigned int)vl[1] << 16);
        lpack.y = (unsigned int)vl[2] | ((unsigned int)vl[3] << 16);
        *(uint2*)(hWhi + off) = hpack;
        *(uint2*)(hWlo + off) = lpack;
    }
#pragma unroll
    for (int j = 0; j < 4; ++j) {
        float p1 = v[j] * a1d, p2 = v[j] * a2d;
#pragma unroll
        for (int o = 32; o > 0; o >>= 1) {
            p1 += __shfl_down(p1, o);
            p2 += __shfl_down(p2, o);
        }
        if (d == 0) { t1[b * N + n0 + wid * 4 + j] = p1; t2[b * N + n0 + wid * 4 + j] = p2; }
    }
}

// ---------------- fused attention: 16 rows/block, w born in A-frag regs ----------------
__global__ __launch_bounds__(256, 4) void k_att(
    const unsigned short* __restrict__ hWhi, const unsigned short* __restrict__ hWlo,
    const float* __restrict__ t1, const float* __restrict__ t2,
    const unsigned long long* __restrict__ packA,
    const float* __restrict__ root_list, int ridx, float* __restrict__ h)
{
    int vb = (blockIdx.x & 7) * 128 + (blockIdx.x >> 3);   // XCD swizzle (1024 blocks)
    int b  = vb >> 6;
    int n0 = (vb & 63) << 4;
    int t = threadIdx.x, lane = t & 63, wid = t >> 6;

    __shared__ float t2s[N];               // 4KB
    __shared__ float redsum[4][16];
    __shared__ float invs[16];
    __shared__ float4v part[4][4][64];     // 16KB: [wid][dt][lane]

    ((float4v*)t2s)[t] = ((const float4v*)(t2 + b * N))[t];
    __syncthreads();

    int r  = lane & 15;
    int qg = wid * 4 + (lane >> 4);        // 0..15: global k-subgroup within a pass
    int n  = n0 + r;
    float t1v = t1[b * N + n];
    const unsigned long long* prow = packA + ((size_t)(b * N + n)) * 16;
    const short8v* BH = (const short8v*)(hWhi + (size_t)b * (N * D));
    const short8v* BL = (const short8v*)(hWlo + (size_t)b * (N * D));

    float4v acc0 = {0,0,0,0}, acc1 = {0,0,0,0}, acc2 = {0,0,0,0}, acc3 = {0,0,0,0};
    float lsum = 0.f;

#pragma unroll 2   // cap unroll: full 8x hoists 64 B-loads -> VGPR spill
    for (int p = 0; p < 8; ++p) {
        int kb = p * 4 + wid;              // this wave's 32-wide k-block
        int bi = (kb * 4) * 64 + lane;
        short8v bh0 = BH[bi], bh1 = BH[bi + 64], bh2 = BH[bi + 128], bh3 = BH[bi + 192];
        short8v bl0 = BL[bi], bl1 = BL[bi + 64], bl2 = BL[bi + 128], bl3 = BL[bi + 192];

        unsigned long long word = prow[p * 2 + (qg >> 3)];
        unsigned int mbyte = (unsigned int)(word >> ((qg & 7) * 8)) & 0xFFu;

        const float* t2p = t2s + p * 128 + qg * 8;
        float4v ta = ((const float4v*)t2p)[0];
        float4v tb = ((const float4v*)t2p)[1];

        float wv[8];
#pragma unroll
        for (int i = 0; i < 8; ++i) {
            float t2v = (i < 4) ? ta[i & 3] : tb[i & 3];
            float e = ((mbyte >> i) & 1u) ? fmaxf(t1v + t2v, 0.f) : 0.f;
            float w = __expf(e);
            wv[i] = w;
            lsum += w;
        }

        AFrag fh, fl;
#pragma unroll
        for (int i = 0; i < 4; ++i)
            split_pair(wv[2 * i], wv[2 * i + 1], fh.u[i], fl.u[i]);

        acc0 = __builtin_amdgcn_mfma_f32_16x16x32_bf16(fh.s, bh0, acc0, 0, 0, 0);
        acc0 = __builtin_amdgcn_mfma_f32_16x16x32_bf16(fh.s, bl0, acc0, 0, 0, 0);
        acc0 = __builtin_amdgcn_mfma_f32_16x16x32_bf16(fl.s, bh0, acc0, 0, 0, 0);
        acc1 = __builtin_amdgcn_mfma_f32_16x16x32_bf16(fh.s, bh1, acc1, 0, 0, 0);
        acc1 = __builtin_amdgcn_mfma_f32_16x16x32_bf16(fh.s, bl1, acc1, 0, 0, 0);
        acc1 = __builtin_amdgcn_mfma_f32_16x16x32_bf16(fl.s, bh1, acc1, 0, 0, 0);
        acc2 = __builtin_amdgcn_mfma_f32_16x16x32_bf16(fh.s, bh2, acc2, 0, 0, 0);
        acc2 = __builtin_amdgcn_mfma_f32_16x16x32_bf16(fh.s, bl2, acc2, 0, 0, 0);
        acc2 = __builtin_amdgcn_mfma_f32_16x16x32_bf16(fl.s, bh2, acc2, 0, 0, 0);
        acc3 = __builtin_amdgcn_mfma_f32_16x16x32_bf16(fh.s, bh3, acc3, 0, 0, 0);
        acc3 = __builtin_amdgcn_mfma_f32_16x16x32_bf16(fh.s, bl3, acc3, 0, 0, 0);
        acc3 = __builtin_amdgcn_mfma_f32_16x16x32_bf16(fl.s, bh3, acc3, 0, 0, 0);
    }

    // per-row softmax denominators: lanes {l, l^16, l^32, l^48} share a row
    lsum += __shfl_xor(lsum, 16);
    lsum += __shfl_xor(lsum, 32);
    if (lane < 16) redsum[wid][lane] = lsum;

    part[wid][0][lane] = acc0;
    part[wid][1][lane] = acc1;
    part[wid][2][lane] = acc2;
    part[wid][3][lane] = acc3;
    __syncthreads();
    if (t < 16) invs[t] = 1.0f / (redsum[0][t] + redsum[1][t] + redsum[2][t] + redsum[3][t]);
    __syncthreads();

    // reduce 4 wave-partials; C mapping: col=lane&15, row=(lane>>4)*4+reg
    int c = t & 63, rg = t >> 6;
    int ls = rg * 16 + (c & 15), dt = c >> 4;
    float4v s = part[0][dt][ls] + part[1][dt][ls] + part[2][dt][ls] + part[3][dt][ls];
    const float* rl = root_list + ((size_t)b * DEPTH + ridx) * N;
#pragma unroll
    for (int reg = 0; reg < 4; ++reg) {
        int rr = rg * 4 + reg;
        if (rl[n0 + rr] > 0.f)
            h[((size_t)(b * N + n0 + rr)) * D + c] = s[reg] * invs[rr];
    }
}

// ---------------- pooling dot: w[b][n] = root>0 ? relu(h.P) : -9e15 ----------------
__global__ __launch_bounds__(256) void k_dotw(const float* __restrict__ h,
                                              const float* __restrict__ root_list,
                                              const float* __restrict__ P,
                                              float* __restrict__ wg) {
    int b = blockIdx.x >> 4, n0 = (blockIdx.x & 15) << 6;
    int t = threadIdx.x;
    int r = n0 + (t >> 2), sub = t & 3;
    const float4* hp = (const float4*)(h + ((size_t)(b * N + r)) * D + sub * 16);
    const float4* pp = (const float4*)(P + sub * 16);
    float s = 0.f;
#pragma unroll
    for (int i = 0; i < 4; ++i) {
        float4 hv = hp[i], pv = pp[i];
        s += hv.x * pv.x + hv.y * pv.y + hv.z * pv.z + hv.w * pv.w;
    }
    s += __shfl_xor(s, 1);
    s += __shfl_xor(s, 2);
    if (sub == 0) {
        float rv = root_list[((size_t)b * DEPTH + 1) * N + r];
        wg[b * N + r] = (rv > 0.f) ? fmaxf(s, 0.f) : -9e15f;
    }
}

// ---------------- softmax + weighted sum + BN-MLP, 1024 threads/batch ----------------
__global__ __launch_bounds__(1024) void k_pool2(const float* __restrict__ h,
                       const float* __restrict__ wg,
                       const float* __restrict__ pW1, const float* __restrict__ pb1,
                       const float* __restrict__ g1, const float* __restrict__ be1,
                       const float* __restrict__ m1, const float* __restrict__ v1,
                       const float* __restrict__ pW2, const float* __restrict__ pb2,
                       const float* __restrict__ g2, const float* __restrict__ be2,
                       const float* __restrict__ m2, const float* __restrict__ v2,
                       const float* __restrict__ pW3, const float* __restrict__ pb3,
                       float* __restrict__ out) {
    int b = blockIdx.x, t = threadIdx.x, lane = t & 63, wid = t >> 6;  // 16 waves
    __shared__ float ws[N];
    __shared__ float red[16];
    __shared__ float part[16][D];
    __shared__ float od[D];
    __shared__ float x1[128];
    __shared__ float x2[64];
    __shared__ float lg[2];

    const float* hb = h + (size_t)b * N * D;
    float sc = wg[b * N + t];

    float lmax = sc;
#pragma unroll
    for (int o = 32; o > 0; o >>= 1) lmax = fmaxf(lmax, __shfl_xor(lmax, o));
    if (lane == 0) red[wid] = lmax;
    __syncthreads();
    float bmax = red[0];
#pragma unroll
    for (int k = 1; k < 16; ++k) bmax = fmaxf(bmax, red[k]);
    __syncthreads();

    float e = __expf(sc - bmax);
    ws[t] = e;
    float lsumv = e;
#pragma unroll
    for (int o = 32; o > 0; o >>= 1) lsumv += __shfl_xor(lsumv, o);
    if (lane == 0) red[wid] = lsumv;
    __syncthreads();
    float bsum = 0.f;
#pragma unroll
    for (int k = 0; k < 16; ++k) bsum += red[k];
    float inv = 1.0f / bsum;

    float acc = 0.f;
    for (int n = wid * 64; n < wid * 64 + 64; ++n) acc += ws[n] * hb[(size_t)n * D + lane];
    part[wid][lane] = acc;
    __syncthreads();
    if (t < D) {
        float s = 0.f;
#pragma unroll
        for (int k = 0; k < 16; ++k) s += part[k][t];
        od[t] = s * inv;
    }
    __syncthreads();

    if (t < 128) {
        float s = pb1[t];
#pragma unroll
        for (int k = 0; k < D; ++k) s += od[k] * pW1[k * 128 + t];
        s = (s - m1[t]) * rsqrtf(v1[t] + BN_EPS) * g1[t] + be1[t];
        x1[t] = fmaxf(s, 0.f);
    }
    __syncthreads();
    if (t < 64) {
        float s = pb2[t];
#pragma unroll
        for (int k = 0; k < 128; ++k) s += x1[k] * pW2[k * 64 + t];
        s = (s - m2[t]) * rsqrtf(v2[t] + BN_EPS) * g2[t] + be2[t];
        x2[t] = fmaxf(s, 0.f);
    }
    __syncthreads();
    if (t < 2) {
        float s = pb3[t];
#pragma unroll
        for (int k = 0; k < 64; ++k) s += x2[k] * pW3[k * 2 + t];
        lg[t] = fmaxf(s, 0.f);
    }
    __syncthreads();
    if (t < 2) {
        float mm = fmaxf(lg[0], lg[1]);
        float e0 = __expf(lg[0] - mm), e1 = __expf(lg[1] - mm);
        out[b * 2 + t] = ((t == 0) ? e0 : e1) / (e0 + e1);
    }
}

extern "C" void kernel_launch(void* const* d_in, const int* in_sizes, int n_in,
                              void* d_out, int out_size, void* d_ws, size_t ws_size,
                              hipStream_t stream) {
    const int*   adj = (const int*)d_in[0];
    const float* X   = (const float*)d_in[1];
    const float* rl  = (const float*)d_in[2];
    const float* W0  = (const float*)d_in[3];
    const float* Wl  = (const float*)d_in[4];
    const float* a1l = (const float*)d_in[5];
    const float* a2l = (const float*)d_in[6];
    const float* P   = (const float*)d_in[7];
    const float* pW1 = (const float*)d_in[8];
    const float* pb1 = (const float*)d_in[9];
    const float* g1  = (const float*)d_in[10];
    const float* be1 = (const float*)d_in[11];
    const float* m1  = (const float*)d_in[12];
    const float* v1  = (const float*)d_in[13];
    const float* pW2 = (const float*)d_in[14];
    const float* pb2 = (const float*)d_in[15];
    const float* g2  = (const float*)d_in[16];
    const float* be2 = (const float*)d_in[17];
    const float* m2  = (const float*)d_in[18];
    const float* v2  = (const float*)d_in[19];
    const float* pW3 = (const float*)d_in[20];
    const float* pb3 = (const float*)d_in[21];
    float* out = (float*)d_out;

    // ws layout: 10,616,832 B total — footprint proven since R3
    float*          h    = (float*)d_ws;                                   // 4MB
    unsigned short* hWhi = (unsigned short*)(h + (size_t)B * N * D);       // 2MB
    unsigned short* hWlo = hWhi + (size_t)B * N * D;                       // 2MB
    float*          t1   = (float*)(hWlo + (size_t)B * N * D);             // 64KB
    float*          t2   = t1 + B * N;                                     // 64KB
    unsigned long long* packA = (unsigned long long*)(t2 + B * N);         // 2MB
    float*          wg   = t1;   // t1 dead after layer loop; reuse for pooling scores

    k_pack<<<B * N * N / 16 / 256, 256, 0, stream>>>(adj, (unsigned short*)packA);
    k_h0<<<B * 64, 256, 0, stream>>>(X, W0, h);
    for (int i = 0; i < DEPTH - 1; ++i) {
        k_hw<<<B * 64, 256, 0, stream>>>(h, Wl + i * D * D, a1l + i * D, a2l + i * D,
                                         hWhi, hWlo, t1, t2);
        k_att<<<B * 64, 256, 0, stream>>>(hWhi, hWlo, t1, t2, packA, rl,
                                          DEPTH - 1 - i, h);
    }
    k_dotw<<<B * 16, 256, 0, stream>>>(h, rl, P, wg);
    k_pool2<<<B, 1024, 0, stream>>>(h, wg, pW1, pb1, g1, be1, m1, v1,
                                    pW2, pb2, g2, be2, m2, v2, pW3, pb3, out);
}